// Round 1
// baseline (292.211 us; speedup 1.0000x reference)
//
#include <hip/hip_runtime.h>
#include <hip/hip_cooperative_groups.h>
#include <math.h>
#include <limits.h>

namespace cg = cooperative_groups;

#define NEV 100000
#define NSL 32                   // slices per batch
#define SLEV (NEV / NSL)         // 3125 events per slice
#define F32EPS 1.1920929e-7f
#define SCALE 524288.0f          // 2^19 fixed-point for num
#define INV_SCALE (1.0f/524288.0f)

typedef unsigned long long u64;

// ws layout (bytes):
//   0          bins: uint2[8][NEV]                 6,400,000
//   6,400,000  binStart: int[8][33]                1,056
//   6,401,056  tref: float[32]                     128
//   6,401,184  fi0P: u64[16][4][2048]              1,048,576
//   7,449,760  fi1P: u64[16][4][8192]              4,194,304
//   11,644,064 histG: int[256][16][32]             524,288
//   12,168,352 cursG: int[256][16][32]             524,288
//   12,692,640 mmB:   int[256][4]                  4,096
#define OFF_BINSTART 6400000
#define OFF_TREF     6401056
#define OFF_FI0P     6401184
#define OFF_FI1P     7449760
#define OFF_HISTG    11644064
#define OFF_CURSG    12168352
#define OFF_MMB      12692640

__device__ __forceinline__ void lds_add64(u64* p, u64 v) {
    __hip_atomic_fetch_add(p, v, __ATOMIC_RELAXED, __HIP_MEMORY_SCOPE_WORKGROUP);
}
__device__ __forceinline__ int lds_add32(int* p, int v) {
    return __hip_atomic_fetch_add(p, v, __ATOMIC_RELAXED, __HIP_MEMORY_SCOPE_WORKGROUP);
}

// One cooperative kernel: 256 blocks x 1024 threads, 1 block/CU co-resident.
// Phases: A hist+minmax | B scan+tref (blk<8) / misc (blk>=8) | C scatter
//         | D splat (2 units/block) | E merge.   4 grid syncs.
__global__ __launch_bounds__(1024, 4) void k_fused(
    const float* __restrict__ f0, const float* __restrict__ f1,
    const float* __restrict__ f2, const float* __restrict__ f3,
    const int* __restrict__ xs, const int* __restrict__ ys,
    const float* __restrict__ ts, const int* __restrict__ ps,
    const float* __restrict__ params, int nP,
    uint2* __restrict__ bins, int* __restrict__ binStart,
    float* __restrict__ tref, u64* __restrict__ fi0P, u64* __restrict__ fi1P,
    int* __restrict__ histG, int* __restrict__ cursG, int* __restrict__ mmB,
    float* __restrict__ out)
{
    cg::grid_group grid = cg::this_grid();
    __shared__ u64 acc[8192];          // 64 KB, aliased per phase
    int*   shi = (int*)acc;
    float* shf = (float*)acc;

    const int tid  = threadIdx.x;
    const int bid  = blockIdx.x;
    const int w    = tid >> 6;
    const int lane = tid & 63;

    // ================= phase A: hist[16 waves][32 bins] + minmax =================
    {
        const int b = bid & 7, sl = bid >> 3;
        const int* yb = ys + b * NEV + sl * SLEV;
        const int* pb = ps + b * NEV + sl * SLEV;
        if (tid < 512) shi[tid] = 0;
        if (tid >= 512 && tid < 516) shi[tid] = (tid & 1) ? -1 : INT_MAX;
        if (bid == 0 && tid == 1023) out[0] = 0.0f;
        __syncthreads();

        int mnP = INT_MAX, mxP = -1, mnN = INT_MAX, mxN = -1;
        const int gbase = sl * SLEV;
        for (int i = tid; i < SLEV; i += 1024) {
            int p = pb[i], y = yb[i];
            int m = (p == 1) ? 0 : 1;
            lds_add32(&shi[w * 32 + m * 16 + (y >> 4)], 1);
            int gi = gbase + i;
            if (m == 0) { mnP = min(mnP, gi); mxP = max(mxP, gi); }
            else        { mnN = min(mnN, gi); mxN = max(mxN, gi); }
        }
        for (int o = 32; o > 0; o >>= 1) {
            mnP = min(mnP, __shfl_down(mnP, o, 64));
            mxP = max(mxP, __shfl_down(mxP, o, 64));
            mnN = min(mnN, __shfl_down(mnN, o, 64));
            mxN = max(mxN, __shfl_down(mxN, o, 64));
        }
        if (lane == 0) {
            atomicMin(&shi[512], mnP); atomicMax(&shi[513], mxP);
            atomicMin(&shi[514], mnN); atomicMax(&shi[515], mxN);
        }
        __syncthreads();
        if (tid < 512) histG[bid * 512 + tid] = shi[tid];
        if (tid < 4)   mmB[bid * 4 + tid] = shi[512 + tid];
    }
    grid.sync();

    // ================= phase B: scan+tref (blk<8) | misc (blk>=8) =================
    if (bid < 8) {
        // LDS: segsum[32][32]=shi[0..1023], segbase=shi[1024..2047],
        //      binTot=shi[2048..2079], bs=shi[2080..2111], mm=shi[2112..2115]
        const int b = bid;
        const int sl = tid >> 5, bin = tid & 31;   // 32 segs (=slices) x 32 bins
        int s = 0;
        #pragma unroll
        for (int wv = 0; wv < 16; ++wv)
            s += histG[((sl * 8 + b) * 16 + wv) * 32 + bin];
        shi[sl * 32 + bin] = s;
        __syncthreads();
        if (tid < 32) {                            // prefix over slices, per bin
            int run = 0;
            for (int g = 0; g < 32; ++g) {
                int v = shi[g * 32 + tid];
                shi[1024 + g * 32 + tid] = run; run += v;
            }
            shi[2048 + tid] = run;
        }
        __syncthreads();
        if (tid == 0) {                            // prefix over bins
            int run = 0;
            for (int k = 0; k < 32; ++k) {
                shi[2080 + k] = run; binStart[b * 33 + k] = run;
                run += shi[2048 + k];
            }
            binStart[b * 33 + 32] = run;
        }
        __syncthreads();
        {   // exact per-(slice,wave,bin) cursors
            int run = shi[2080 + bin] + shi[1024 + sl * 32 + bin];
            #pragma unroll
            for (int wv = 0; wv < 16; ++wv) {
                int idx = ((sl * 8 + b) * 16 + wv) * 32 + bin;
                int h = histG[idx];
                cursG[idx] = run; run += h;
            }
        }
        if (tid < 4) {                             // minmax over 32 slice-blocks
            int c = tid;
            int v = (c == 0 || c == 2) ? INT_MAX : -1;
            for (int sl2 = 0; sl2 < 32; ++sl2) {
                int x = mmB[(sl2 * 8 + b) * 4 + c];
                v = (c == 0 || c == 2) ? min(v, x) : max(v, x);
            }
            shi[2112 + c] = v;
        }
        __syncthreads();
        if (tid == 0) {
            const float* tb = ts + b * NEV;
            int mnP = shi[2112], mxP = shi[2113], mnN = shi[2114], mxN = shi[2115];
            int fP = (mnP == INT_MAX) ? 0 : mnP;
            int lP = (mxP < 0) ? (NEV - 1) : mxP;
            int fN = (mnN == INT_MAX) ? 0 : mnN;
            int lN = (mxN < 0) ? (NEV - 1) : mxN;
            tref[b * 4 + 0] = tb[lP];  // pos fwd
            tref[b * 4 + 1] = tb[fP];  // pos bwd
            tref[b * 4 + 2] = tb[lN];  // neg fwd
            tref[b * 4 + 3] = tb[fN];  // neg bwd
        }
    } else {
        // misc: weight decay + smoothness, overlapped with the scan
        float s = 0.0f;
        const int gtid = (bid - 8) * 1024 + tid;
        const int gstride = 248 * 1024;

        int n4 = nP >> 2;
        const float4* p4 = (const float4*)params;
        float wsum = 0.0f;
        for (int i = gtid; i < n4; i += gstride) {
            float4 v = p4[i];
            wsum += v.x * v.x + v.y * v.y + v.z * v.z + v.w * v.w;
        }
        if (gtid == 0) for (int i = n4 * 4; i < nP; ++i) wsum += params[i] * params[i];
        s += wsum * 5e-5f;

        const int nTot = 1392640;
        for (int idx = gtid; idx < nTot; idx += gstride) {
            int fi, off, logW;
            if (idx < 16384)       { fi = 0; off = 0;      logW = 5; }
            else if (idx < 81920)  { fi = 1; off = 16384;  logW = 6; }
            else if (idx < 344064) { fi = 2; off = 81920;  logW = 7; }
            else                   { fi = 3; off = 344064; logW = 8; }
            const float* f = (fi == 0) ? f0 : (fi == 1) ? f1 : (fi == 2) ? f2 : f3;
            int W = 1 << logW;
            int local = idx - off;
            int x = local & (W - 1);
            int y = (local >> logW) & (W - 1);
            float c_lr = 6.25f / (float)(16 * W * (W - 1));
            float c_dd = 6.25f / (float)(16 * (W - 1) * (W - 1));
            float v = f[local];
            bool xok = x < W - 1;
            bool yok = y < W - 1;
            float vr = xok ? f[local + 1] : 0.0f;
            float vd = yok ? f[local + W] : 0.0f;
            if (xok) { float d = vr - v; s += c_lr * __powf(d * d + 1e-6f, 0.45f); }
            if (yok) { float d = vd - v; s += c_lr * __powf(d * d + 1e-6f, 0.45f); }
            if (xok && yok) {
                float d1 = f[local + W + 1] - v;
                s += c_dd * __powf(d1 * d1 + 1e-6f, 0.45f);
                float d2 = vr - vd;
                s += c_dd * __powf(d2 * d2 + 1e-6f, 0.45f);
            }
        }
        for (int o = 32; o > 0; o >>= 1) s += __shfl_down(s, o, 64);
        __syncthreads();
        if (lane == 0) shf[w] = s;
        __syncthreads();
        if (tid == 0) {
            float tot = 0.0f;
            for (int k = 0; k < 16; ++k) tot += shf[k];
            atomicAdd(out, tot);
        }
    }
    grid.sync();

    // ================= phase C: scatter into bins =================
    {
        const int b = bid & 7, sl = bid >> 3;
        const int*   xb  = xs + b * NEV + sl * SLEV;
        const int*   yb  = ys + b * NEV + sl * SLEV;
        const float* tb2 = ts + b * NEV + sl * SLEV;
        const int*   pb  = ps + b * NEV + sl * SLEV;
        uint2* ob = bins + b * NEV;

        if (tid < 512) shi[tid] = cursG[bid * 512 + tid];
        __syncthreads();
        for (int i = tid; i < SLEV; i += 1024) {
            int p = pb[i], x = xb[i], y = yb[i];
            float t = tb2[i];
            int m = (p == 1) ? 0 : 1;
            int bin = m * 16 + (y >> 4);
            int pos = lds_add32(&shi[w * 32 + bin], 1);
            ob[pos] = make_uint2((unsigned)(x | (y << 8)), __float_as_uint(t));
        }
    }
    grid.sync();

    // ================= phase D: splat (2 units per block) =================
    for (int u = 0; u < 2; ++u) {
        const int unit = bid + u * 256;      // u=0: fi0/fi1/fi2, u=1: fi3 (balanced)
        const int b = unit & 7;
        const int rm = unit >> 3;
        const int m = rm & 1;
        const int role = rm >> 1;            // 0..31
        const int bm = b * 2 + m;

        int fi, row0 = 0, nrows, lo, hi, slice = 0, nslice = 1, mode;
        if (role < 4)       { fi = 0; mode = 0; slice = role;     nslice = 4; nrows = 32; lo = 0; hi = 15; }
        else if (role < 8)  { fi = 1; mode = 0; slice = role - 4; nslice = 4; nrows = 64; lo = 0; hi = 15; }
        else if (role < 16) { int c = role - 8;  fi = 2; mode = 1; row0 = 16 * c; nrows = 16;
                              lo = max(0, 2 * c - 1); hi = min(15, 2 * c + 2); }
        else                { int c = role - 16; fi = 3; mode = 1; row0 = 16 * c; nrows = 16;
                              lo = max(0, c - 1); hi = min(15, c + 1); }

        const int W = 32 << fi;
        const int sh = 3 - fi;
        const int planeN = (fi == 0) ? 1024 : (fi == 1) ? 4096 : nrows * W;
        const int used = (fi == 0) ? 8192 : 2 * planeN;
        const int rowEnd = row0 + nrows;
        const float Wm1 = (float)(W - 1);

        const float* flow = (fi == 0) ? f0 : (fi == 1) ? f1 : (fi == 2) ? f2 : f3;
        const float* fxp = flow + (size_t)b * 2 * W * W;
        const float* fyp = fxp + W * W;

        __syncthreads();                     // protect previous unit's LDS reads
        for (int i = tid; i < used; i += 1024) acc[i] = 0ULL;
        __syncthreads();

        const float trF = tref[b * 4 + m * 2 + 0];
        const float trB = tref[b * 4 + m * 2 + 1];
        const int s0 = binStart[b * 33 + m * 16 + lo];
        const int e0 = binStart[b * 33 + m * 16 + hi + 1];
        const uint2* eb = bins + b * NEV;
        const int rep = (fi == 0) ? (((tid >> 4) & 3) * 2048) : 0;

        for (int i = s0 + slice * 1024 + tid; i < e0; i += nslice * 1024) {
            uint2 ev = eb[i];
            int x = ev.x & 255;
            int y = (ev.x >> 8) & 255;
            float t = __uint_as_float(ev.y);
            int xi = x >> sh, yi = y >> sh;
            float fx = fxp[yi * W + xi];
            float fy = fyp[yi * W + xi];
            float tF = trF - t + F32EPS;
            float tB = trB - t - F32EPS;
            #pragma unroll
            for (int dir = 0; dir < 2; ++dir) {
                float t_ = dir ? tB : tF;
                float x_ = fminf(fmaxf((float)xi + t_ * fx, 0.0f), Wm1);
                float y_ = fminf(fmaxf((float)yi + t_ * fy, 0.0f), Wm1);
                float x0f = floorf(x_), y0f = floorf(y_);
                float x0w = x_ - x0f, x1w = 1.0f - x0w;
                float y0w = y_ - y0f, y1w = 1.0f - y0w;
                int x0i = (int)x0f, y0i = (int)y0f;
                int x1i = min(x0i + 1, W - 1);
                int y1i = min(y0i + 1, W - 1);
                u64 Pa = (1ULL << 32) | (u64)(unsigned)(x0w * y0w * t * SCALE);
                u64 Pb = (1ULL << 32) | (u64)(unsigned)(x1w * y0w * t * SCALE);
                u64 Pc = (1ULL << 32) | (u64)(unsigned)(x0w * y1w * t * SCALE);
                u64 Pd = (1ULL << 32) | (u64)(unsigned)(x1w * y1w * t * SCALE);
                int base = rep + dir * planeN;
                if (mode == 0) {
                    int r1 = base + y1i * W;
                    int r0 = base + y0i * W;
                    lds_add64(&acc[r1 + x1i], Pa);
                    lds_add64(&acc[r1 + x0i], Pb);
                    lds_add64(&acc[r0 + x1i], Pc);
                    lds_add64(&acc[r0 + x0i], Pd);
                } else {
                    if (y1i >= row0 && y1i < rowEnd) {
                        int r = base + (y1i - row0) * W;
                        lds_add64(&acc[r + x1i], Pa);
                        lds_add64(&acc[r + x0i], Pb);
                    }
                    if (y0i >= row0 && y0i < rowEnd) {
                        int r = base + (y0i - row0) * W;
                        lds_add64(&acc[r + x1i], Pc);
                        lds_add64(&acc[r + x0i], Pd);
                    }
                }
            }
        }
        __syncthreads();

        if (mode == 0) {
            if (fi == 0) {
                for (int j = tid; j < 2048; j += 1024)
                    fi0P[(bm * 4 + slice) * 2048 + j] =
                        acc[j] + acc[j + 2048] + acc[j + 4096] + acc[j + 6144];
            } else {
                for (int j = tid; j < 8192; j += 1024)
                    fi1P[(bm * 4 + slice) * 8192 + j] = acc[j];
            }
        } else {
            float s = 0.0f;
            for (int j = tid; j < used; j += 1024) {
                u64 v = acc[j];
                float num = (float)(unsigned)(v & 0xffffffffULL) * INV_SCALE;
                float den = (float)(unsigned)(v >> 32);
                float r = num / (den + F32EPS);
                s += sqrtf(r * r + 1e-6f);
            }
            for (int o = 32; o > 0; o >>= 1) s += __shfl_down(s, o, 64);
            __syncthreads();
            if (lane == 0) shf[w] = s;
            __syncthreads();
            if (tid == 0) {
                float tot = 0.0f;
                for (int k = 0; k < 16; ++k) tot += shf[k];
                atomicAdd(out, tot);
            }
        }
    }
    grid.sync();

    // ================= phase E: merge fi0/fi1 partials =================
    {
        const int idx = bid * 1024 + tid;     // blocks 0..159 fully active
        if (idx < 163840) {
            u64 v = 0;
            if (idx < 32768) {
                int bm = idx >> 11, j = idx & 2047;
                const u64* p = fi0P + (bm * 4) * 2048 + j;
                #pragma unroll
                for (int s2 = 0; s2 < 4; ++s2) v += p[s2 * 2048];
            } else {
                int r = idx - 32768;
                int bm = r >> 13, j = r & 8191;
                const u64* p = fi1P + (bm * 4) * 8192 + j;
                #pragma unroll
                for (int s2 = 0; s2 < 4; ++s2) v += p[s2 * 8192];
            }
            float num = (float)(unsigned)(v & 0xffffffffULL) * INV_SCALE;
            float den = (float)(unsigned)(v >> 32);
            float r2 = num / (den + F32EPS);
            float sv = sqrtf(r2 * r2 + 1e-6f);
            for (int o = 32; o > 0; o >>= 1) sv += __shfl_down(sv, o, 64);
            __syncthreads();
            if (lane == 0) shf[w] = sv;
            __syncthreads();
            if (tid == 0) {
                float tot = 0.0f;
                for (int k = 0; k < 16; ++k) tot += shf[k];
                atomicAdd(out, tot);
            }
        }
    }
}

extern "C" void kernel_launch(void* const* d_in, const int* in_sizes, int n_in,
                              void* d_out, int out_size, void* d_ws, size_t ws_size,
                              hipStream_t stream) {
    const float* f0 = (const float*)d_in[0];
    const float* f1 = (const float*)d_in[1];
    const float* f2 = (const float*)d_in[2];
    const float* f3 = (const float*)d_in[3];
    const int*   xs = (const int*)d_in[4];
    const int*   ys = (const int*)d_in[5];
    const float* ts = (const float*)d_in[6];
    const int*   ps = (const int*)d_in[7];
    const float* params = (const float*)d_in[10];
    int nP = in_sizes[10];
    float* out = (float*)d_out;

    char* ws = (char*)d_ws;
    uint2* bins     = (uint2*)ws;
    int*   binStart = (int*)(ws + OFF_BINSTART);
    float* tref     = (float*)(ws + OFF_TREF);
    u64*   fi0P     = (u64*)(ws + OFF_FI0P);
    u64*   fi1P     = (u64*)(ws + OFF_FI1P);
    int*   histG    = (int*)(ws + OFF_HISTG);
    int*   cursG    = (int*)(ws + OFF_CURSG);
    int*   mmB      = (int*)(ws + OFF_MMB);

    void* args[] = { (void*)&f0, (void*)&f1, (void*)&f2, (void*)&f3,
                     (void*)&xs, (void*)&ys, (void*)&ts, (void*)&ps,
                     (void*)&params, (void*)&nP,
                     (void*)&bins, (void*)&binStart, (void*)&tref,
                     (void*)&fi0P, (void*)&fi1P, (void*)&histG, (void*)&cursG,
                     (void*)&mmB, (void*)&out };
    hipLaunchCooperativeKernel(k_fused, dim3(256), dim3(1024), args, 0, stream);
}

// Round 2
// 187.950 us; speedup vs baseline: 1.5547x; 1.5547x over previous
//
#include <hip/hip_runtime.h>
#include <math.h>
#include <limits.h>

#define NEV 100000
#define NB 8
#define NSL 32                   // slices per batch
#define SLEV (NEV / NSL)         // 3125 events per slice
#define F32EPS 1.1920929e-7f
#define SCALE 524288.0f          // 2^19 fixed-point for num
#define INV_SCALE (1.0f/524288.0f)

typedef unsigned long long u64;

// ws layout (bytes):
//   0          bins: uint2[8][NEV]                 6,400,000
//   6,400,000  binStart: int[8][33]                1,056
//   6,401,056  tref: float[32]                     128
//   6,401,184  fi0P: u64[16][4][2048]              1,048,576
//   7,449,760  fi1P: u64[16][4][8192]              4,194,304
//   11,644,064 histG: int[256][4][32]              131,072
//   11,775,136 cursG: int[256][4][32]              131,072
//   11,906,208 mmG:   int[256][4]                  4,096
#define OFF_BINSTART 6400000
#define OFF_TREF     6401056
#define OFF_FI0P     6401184
#define OFF_FI1P     7449760
#define OFF_HISTG    11644064
#define OFF_CURSG    11775136
#define OFF_MMG      11906208

__device__ __forceinline__ void lds_add64(u64* p, u64 v) {
    __hip_atomic_fetch_add(p, v, __ATOMIC_RELAXED, __HIP_MEMORY_SCOPE_WORKGROUP);
}
__device__ __forceinline__ int lds_add32(int* p, int v) {
    return __hip_atomic_fetch_add(p, v, __ATOMIC_RELAXED, __HIP_MEMORY_SCOPE_WORKGROUP);
}

// =============== pass 1: per-(slice,wave) histograms + per-slice minmax ===============
// 256 blocks x 256 threads; bid = sl*8 + b
__global__ __launch_bounds__(256) void k_hist(
    const int* __restrict__ ys, const int* __restrict__ ps,
    int* __restrict__ histG, int* __restrict__ mmG) {
    int bid = blockIdx.x;
    int b = bid & 7;
    int sl = bid >> 3;
    int tid = threadIdx.x;
    int w = tid >> 6, lane = tid & 63;

    const int* yb = ys + b * NEV + sl * SLEV;
    const int* pb = ps + b * NEV + sl * SLEV;

    __shared__ int hist[4][32];
    __shared__ int mm[4];
    if (tid < 128) hist[tid >> 5][tid & 31] = 0;
    if (tid == 0) { mm[0] = INT_MAX; mm[1] = -1; mm[2] = INT_MAX; mm[3] = -1; }
    __syncthreads();

    int mnP = INT_MAX, mxP = -1, mnN = INT_MAX, mxN = -1;
    int gbase = sl * SLEV;
    for (int i = w * 64 + lane; i < SLEV; i += 256) {
        int p = pb[i];
        int y = yb[i];
        int m = (p == 1) ? 0 : 1;
        lds_add32(&hist[w][m * 16 + (y >> 4)], 1);
        int gi = gbase + i;
        if (m == 0) { mnP = min(mnP, gi); mxP = max(mxP, gi); }
        else        { mnN = min(mnN, gi); mxN = max(mxN, gi); }
    }
    for (int o = 32; o > 0; o >>= 1) {
        mnP = min(mnP, __shfl_down(mnP, o, 64));
        mxP = max(mxP, __shfl_down(mxP, o, 64));
        mnN = min(mnN, __shfl_down(mnN, o, 64));
        mxN = max(mxN, __shfl_down(mxN, o, 64));
    }
    if (lane == 0) {
        atomicMin(&mm[0], mnP); atomicMax(&mm[1], mxP);
        atomicMin(&mm[2], mnN); atomicMax(&mm[3], mxN);
    }
    __syncthreads();
    if (tid < 128) histG[(bid * 4 + (tid >> 5)) * 32 + (tid & 31)] = hist[tid >> 5][tid & 31];
    if (tid < 4)   mmG[bid * 4 + tid] = mm[tid];
}

// =============== pass 2: parallel prefix + tref + zero out (8 blocks x 1024) ===============
__global__ __launch_bounds__(1024) void k_scan(
    const int* __restrict__ histG, const int* __restrict__ mmG,
    const float* __restrict__ ts,
    int* __restrict__ cursG, int* __restrict__ binStart,
    float* __restrict__ tref, float* __restrict__ out) {
    int b = blockIdx.x;            // one block per batch
    int tid = threadIdx.x;
    int sl = tid >> 5, bin = tid & 31;   // 32 slices x 32 bins

    __shared__ int seg[32][32];      // per-(slice,bin) totals (4 waves summed)
    __shared__ int segbase[32][32];  // exclusive prefix over slices
    __shared__ int binTot[32];
    __shared__ int binBase[33];
    __shared__ int mm[4];

    int s = 0;
    #pragma unroll
    for (int w = 0; w < 4; ++w)
        s += histG[((sl * 8 + b) * 4 + w) * 32 + bin];
    seg[sl][bin] = s;
    __syncthreads();

    if (tid < 32) {                  // prefix over slices, per bin
        int run = 0;
        for (int g = 0; g < 32; ++g) {
            segbase[g][tid] = run; run += seg[g][tid];
        }
        binTot[tid] = run;
    }
    __syncthreads();
    if (tid == 0) {                  // prefix over bins
        int run = 0;
        for (int k = 0; k < 32; ++k) {
            binBase[k] = run; binStart[b * 33 + k] = run;
            run += binTot[k];
        }
        binBase[32] = run;
        binStart[b * 33 + 32] = run;
    }
    if (b == 0 && tid == 512) out[0] = 0.0f;
    __syncthreads();

    {   // exact per-(slice,wave,bin) cursors, slice-parallel
        int run = binBase[bin] + segbase[sl][bin];
        #pragma unroll
        for (int w = 0; w < 4; ++w) {
            int idx = ((sl * 8 + b) * 4 + w) * 32 + bin;
            int h = histG[idx];
            cursG[idx] = run; run += h;
        }
    }

    if (tid < 4) {                   // minmax over 32 slice-blocks
        int c = tid;
        int v = (c == 0 || c == 2) ? INT_MAX : -1;
        for (int sl2 = 0; sl2 < 32; ++sl2) {
            int x = mmG[(sl2 * 8 + b) * 4 + c];
            v = (c == 0 || c == 2) ? min(v, x) : max(v, x);
        }
        mm[c] = v;
    }
    __syncthreads();
    if (tid == 0) {
        const float* tb = ts + b * NEV;
        int mnP = mm[0], mxP = mm[1], mnN = mm[2], mxN = mm[3];
        int fP = (mnP == INT_MAX) ? 0 : mnP;
        int lP = (mxP < 0) ? (NEV - 1) : mxP;
        int fN = (mnN == INT_MAX) ? 0 : mnN;
        int lN = (mxN < 0) ? (NEV - 1) : mxN;
        tref[b * 4 + 0] = tb[lP];  // pos fwd
        tref[b * 4 + 1] = tb[fP];  // pos bwd
        tref[b * 4 + 2] = tb[lN];  // neg fwd
        tref[b * 4 + 3] = tb[fN];  // neg bwd
    }
}

// =============== pass 3: scatter into bins using exact per-wave cursors ===============
__global__ __launch_bounds__(256) void k_scatter(
    const int* __restrict__ xs, const int* __restrict__ ys,
    const float* __restrict__ ts, const int* __restrict__ ps,
    const int* __restrict__ cursG, uint2* __restrict__ bins) {
    int bid = blockIdx.x;
    int b = bid & 7;
    int sl = bid >> 3;
    int tid = threadIdx.x;
    int w = tid >> 6, lane = tid & 63;

    const int*   xb = xs + b * NEV + sl * SLEV;
    const int*   yb = ys + b * NEV + sl * SLEV;
    const float* tb = ts + b * NEV + sl * SLEV;
    const int*   pb = ps + b * NEV + sl * SLEV;
    uint2* ob = bins + b * NEV;

    __shared__ int curs[4][32];
    if (tid < 128) curs[tid >> 5][tid & 31] = cursG[(bid * 4 + (tid >> 5)) * 32 + (tid & 31)];
    __syncthreads();

    for (int i = w * 64 + lane; i < SLEV; i += 256) {
        int p = pb[i];
        int x = xb[i];
        int y = yb[i];
        float t = tb[i];
        int m = (p == 1) ? 0 : 1;
        int bin = m * 16 + (y >> 4);
        int pos = lds_add32(&curs[w][bin], 1);
        ob[pos] = make_uint2((unsigned)(x | (y << 8)), __float_as_uint(t));
    }
}

// =============== event splat: 512 blocks = exactly 2/CU, no tail ===============
__global__ __launch_bounds__(1024) void k_splat(
    const float* __restrict__ f0, const float* __restrict__ f1,
    const float* __restrict__ f2, const float* __restrict__ f3,
    const uint2* __restrict__ bins, const int* __restrict__ binStart,
    const float* __restrict__ tref,
    u64* __restrict__ fi0P, u64* __restrict__ fi1P,
    float* __restrict__ out) {
    __shared__ u64 acc[8192];   // 64 KB
    __shared__ float red[16];

    int tid = threadIdx.x;
    int bid = blockIdx.x;
    int b = bid & 7;
    int rm = bid >> 3;          // 0..63
    int m = rm & 1;
    int role = rm >> 1;         // 0..31
    int bm = b * 2 + m;

    int fi, row0 = 0, nrows, lo, hi, slice = 0, nslice = 1, mode;
    if (role < 4)       { fi = 0; mode = 0; slice = role;     nslice = 4; nrows = 32; lo = 0; hi = 15; }
    else if (role < 8)  { fi = 1; mode = 0; slice = role - 4; nslice = 4; nrows = 64; lo = 0; hi = 15; }
    else if (role < 16) { int c = role - 8;  fi = 2; mode = 1; row0 = 16 * c; nrows = 16;
                          lo = max(0, 2 * c - 1); hi = min(15, 2 * c + 2); }
    else                { int c = role - 16; fi = 3; mode = 1; row0 = 16 * c; nrows = 16;
                          lo = max(0, c - 1); hi = min(15, c + 1); }

    int W = 32 << fi;
    int sh = 3 - fi;
    int planeN = (fi == 0) ? 1024 : (fi == 1) ? 4096 : nrows * W;
    int used = (fi == 0) ? 8192 : 2 * planeN;
    int rowEnd = row0 + nrows;
    float Wm1 = (float)(W - 1);

    const float* flow = (fi == 0) ? f0 : (fi == 1) ? f1 : (fi == 2) ? f2 : f3;
    const float* fxp = flow + (size_t)b * 2 * W * W;
    const float* fyp = fxp + W * W;

    for (int i = tid; i < used; i += 1024) acc[i] = 0ULL;
    __syncthreads();

    float trF = tref[b * 4 + m * 2 + 0];
    float trB = tref[b * 4 + m * 2 + 1];

    int s0 = binStart[b * 33 + m * 16 + lo];
    int e0 = binStart[b * 33 + m * 16 + hi + 1];
    const uint2* eb = bins + b * NEV;

    int rep = (fi == 0) ? (((tid >> 4) & 3) * 2048) : 0;

    for (int i = s0 + slice * 1024 + tid; i < e0; i += nslice * 1024) {
        uint2 ev = eb[i];
        int x = ev.x & 255;
        int y = (ev.x >> 8) & 255;
        float t = __uint_as_float(ev.y);
        int xi = x >> sh, yi = y >> sh;
        float fx = fxp[yi * W + xi];
        float fy = fyp[yi * W + xi];
        float tF = trF - t + F32EPS;
        float tB = trB - t - F32EPS;
        #pragma unroll
        for (int dir = 0; dir < 2; ++dir) {
            float t_ = dir ? tB : tF;
            float x_ = fminf(fmaxf((float)xi + t_ * fx, 0.0f), Wm1);
            float y_ = fminf(fmaxf((float)yi + t_ * fy, 0.0f), Wm1);
            float x0f = floorf(x_), y0f = floorf(y_);
            float x0w = x_ - x0f, x1w = 1.0f - x0w;
            float y0w = y_ - y0f, y1w = 1.0f - y0w;
            int x0i = (int)x0f, y0i = (int)y0f;
            int x1i = min(x0i + 1, W - 1);
            int y1i = min(y0i + 1, W - 1);
            u64 Pa = (1ULL << 32) | (u64)(unsigned)(x0w * y0w * t * SCALE);
            u64 Pb = (1ULL << 32) | (u64)(unsigned)(x1w * y0w * t * SCALE);
            u64 Pc = (1ULL << 32) | (u64)(unsigned)(x0w * y1w * t * SCALE);
            u64 Pd = (1ULL << 32) | (u64)(unsigned)(x1w * y1w * t * SCALE);
            int base = rep + dir * planeN;
            if (mode == 0) {
                int r1 = base + y1i * W;
                int r0 = base + y0i * W;
                lds_add64(&acc[r1 + x1i], Pa);
                lds_add64(&acc[r1 + x0i], Pb);
                lds_add64(&acc[r0 + x1i], Pc);
                lds_add64(&acc[r0 + x0i], Pd);
            } else {
                if (y1i >= row0 && y1i < rowEnd) {
                    int r = base + (y1i - row0) * W;
                    lds_add64(&acc[r + x1i], Pa);
                    lds_add64(&acc[r + x0i], Pb);
                }
                if (y0i >= row0 && y0i < rowEnd) {
                    int r = base + (y0i - row0) * W;
                    lds_add64(&acc[r + x1i], Pc);
                    lds_add64(&acc[r + x0i], Pd);
                }
            }
        }
    }
    __syncthreads();

    if (mode == 0) {
        if (fi == 0) {
            for (int j = tid; j < 2048; j += 1024)
                fi0P[(bm * 4 + slice) * 2048 + j] =
                    acc[j] + acc[j + 2048] + acc[j + 4096] + acc[j + 6144];
        } else {
            for (int j = tid; j < 8192; j += 1024)
                fi1P[(bm * 4 + slice) * 8192 + j] = acc[j];
        }
        return;
    }

    float s = 0.0f;
    for (int j = tid; j < used; j += 1024) {
        u64 v = acc[j];
        float num = (float)(unsigned)(v & 0xffffffffULL) * INV_SCALE;
        float den = (float)(unsigned)(v >> 32);
        float r = num / (den + F32EPS);
        s += sqrtf(r * r + 1e-6f);
    }
    for (int o = 32; o > 0; o >>= 1) s += __shfl_down(s, o, 64);
    if ((tid & 63) == 0) red[tid >> 6] = s;
    __syncthreads();
    if (tid == 0) {
        float tot = 0.0f;
        for (int w2 = 0; w2 < 16; ++w2) tot += red[w2];
        atomicAdd(out, tot);
    }
}

// =============== merge fi0/fi1 partials (4 slices each) -> loss terms ===============
__global__ __launch_bounds__(256) void k_merge(const u64* __restrict__ fi0P,
                                               const u64* __restrict__ fi1P,
                                               float* __restrict__ out) {
    int idx = blockIdx.x * 256 + threadIdx.x;   // < 163840
    u64 v = 0;
    if (idx < 32768) {
        int bm = idx >> 11, j = idx & 2047;
        const u64* p = fi0P + (bm * 4) * 2048 + j;
        #pragma unroll
        for (int s = 0; s < 4; ++s) v += p[s * 2048];
    } else {
        int r = idx - 32768;
        int bm = r >> 13, j = r & 8191;
        const u64* p = fi1P + (bm * 4) * 8192 + j;
        #pragma unroll
        for (int s = 0; s < 4; ++s) v += p[s * 8192];
    }
    float num = (float)(unsigned)(v & 0xffffffffULL) * INV_SCALE;
    float den = (float)(unsigned)(v >> 32);
    float r = num / (den + F32EPS);
    float s = sqrtf(r * r + 1e-6f);
    for (int o = 32; o > 0; o >>= 1) s += __shfl_down(s, o, 64);
    __shared__ float red[4];
    if ((threadIdx.x & 63) == 0) red[threadIdx.x >> 6] = s;
    __syncthreads();
    if (threadIdx.x == 0)
        atomicAdd(out, red[0] + red[1] + red[2] + red[3]);
}

// =============== weight decay + smoothness ===============
__global__ __launch_bounds__(256) void k_misc(
    const float* __restrict__ params, int nP,
    const float* __restrict__ f0, const float* __restrict__ f1,
    const float* __restrict__ f2, const float* __restrict__ f3,
    float* __restrict__ out) {
    float s = 0.0f;
    int gstride = gridDim.x * blockDim.x;
    int gtid = blockIdx.x * blockDim.x + threadIdx.x;

    int n4 = nP >> 2;
    const float4* p4 = (const float4*)params;
    float w = 0.0f;
    for (int i = gtid; i < n4; i += gstride) {
        float4 v = p4[i];
        w += v.x * v.x + v.y * v.y + v.z * v.z + v.w * v.w;
    }
    if (gtid == 0) for (int i = n4 * 4; i < nP; ++i) w += params[i] * params[i];
    s += w * 5e-5f;

    const int nTot = 1392640;
    for (int idx = gtid; idx < nTot; idx += gstride) {
        int fi, off, logW;
        if (idx < 16384)       { fi = 0; off = 0;      logW = 5; }
        else if (idx < 81920)  { fi = 1; off = 16384;  logW = 6; }
        else if (idx < 344064) { fi = 2; off = 81920;  logW = 7; }
        else                   { fi = 3; off = 344064; logW = 8; }
        const float* f = (fi == 0) ? f0 : (fi == 1) ? f1 : (fi == 2) ? f2 : f3;
        int W = 1 << logW;
        int local = idx - off;
        int x = local & (W - 1);
        int y = (local >> logW) & (W - 1);
        float c_lr = 6.25f / (float)(16 * W * (W - 1));
        float c_dd = 6.25f / (float)(16 * (W - 1) * (W - 1));
        float v = f[local];
        bool xok = x < W - 1;
        bool yok = y < W - 1;
        float vr = xok ? f[local + 1] : 0.0f;
        float vd = yok ? f[local + W] : 0.0f;
        if (xok) { float d = vr - v; s += c_lr * __powf(d * d + 1e-6f, 0.45f); }
        if (yok) { float d = vd - v; s += c_lr * __powf(d * d + 1e-6f, 0.45f); }
        if (xok && yok) {
            float d1 = f[local + W + 1] - v;
            s += c_dd * __powf(d1 * d1 + 1e-6f, 0.45f);
            float d2 = vr - vd;
            s += c_dd * __powf(d2 * d2 + 1e-6f, 0.45f);
        }
    }

    for (int o = 32; o > 0; o >>= 1) s += __shfl_down(s, o, 64);
    __shared__ float red[4];
    if ((threadIdx.x & 63) == 0) red[threadIdx.x >> 6] = s;
    __syncthreads();
    if (threadIdx.x == 0)
        atomicAdd(out, red[0] + red[1] + red[2] + red[3]);
}

extern "C" void kernel_launch(void* const* d_in, const int* in_sizes, int n_in,
                              void* d_out, int out_size, void* d_ws, size_t ws_size,
                              hipStream_t stream) {
    const float* f0 = (const float*)d_in[0];
    const float* f1 = (const float*)d_in[1];
    const float* f2 = (const float*)d_in[2];
    const float* f3 = (const float*)d_in[3];
    const int*   xs = (const int*)d_in[4];
    const int*   ys = (const int*)d_in[5];
    const float* ts = (const float*)d_in[6];
    const int*   ps = (const int*)d_in[7];
    const float* params = (const float*)d_in[10];
    float* out = (float*)d_out;

    char* ws = (char*)d_ws;
    uint2* bins     = (uint2*)ws;
    int*   binStart = (int*)(ws + OFF_BINSTART);
    float* tref     = (float*)(ws + OFF_TREF);
    u64*   fi0P     = (u64*)(ws + OFF_FI0P);
    u64*   fi1P     = (u64*)(ws + OFF_FI1P);
    int*   histG    = (int*)(ws + OFF_HISTG);
    int*   cursG    = (int*)(ws + OFF_CURSG);
    int*   mmG      = (int*)(ws + OFF_MMG);

    hipLaunchKernelGGL(k_hist, dim3(NB * NSL), dim3(256), 0, stream, ys, ps, histG, mmG);
    hipLaunchKernelGGL(k_scan, dim3(NB), dim3(1024), 0, stream,
                       histG, mmG, ts, cursG, binStart, tref, out);
    hipLaunchKernelGGL(k_scatter, dim3(NB * NSL), dim3(256), 0, stream,
                       xs, ys, ts, ps, cursG, bins);
    hipLaunchKernelGGL(k_splat, dim3(512), dim3(1024), 0, stream,
                       f0, f1, f2, f3, bins, binStart, tref, fi0P, fi1P, out);
    hipLaunchKernelGGL(k_merge, dim3(640), dim3(256), 0, stream, fi0P, fi1P, out);
    hipLaunchKernelGGL(k_misc, dim3(1024), dim3(256), 0, stream,
                       params, in_sizes[10], f0, f1, f2, f3, out);
}

// Round 3
// 183.930 us; speedup vs baseline: 1.5887x; 1.0219x over previous
//
#include <hip/hip_runtime.h>
#include <math.h>
#include <limits.h>

#define NEV 100000
#define NB 8
#define NSL 32                   // slices per batch
#define SLEV (NEV / NSL)         // 3125 events per slice
#define F32EPS 1.1920929e-7f
#define SCALE 524288.0f          // 2^19 fixed-point for num
#define INV_SCALE (1.0f/524288.0f)

typedef unsigned long long u64;

// ws layout (bytes):
//   0          bins: uint2[8][NEV]                 6,400,000
//   6,400,000  binStart: int[8][33]                1,056
//   6,401,056  tref: float[32]                     128
//   6,401,184  fi0P: u64[16][4][2048]              1,048,576
//   7,449,760  fi1P: u64[16][4][8192]              4,194,304
//   11,644,064 histG: int[256][4][32]              131,072
//   11,775,136 mmG:   int[256][4]                  4,096
//   11,779,232 miscP: float[256]                   1,024
#define OFF_BINSTART 6400000
#define OFF_TREF     6401056
#define OFF_FI0P     6401184
#define OFF_FI1P     7449760
#define OFF_HISTG    11644064
#define OFF_MMG      11775136
#define OFF_MISCP    11779232

__device__ __forceinline__ void lds_add64(u64* p, u64 v) {
    __hip_atomic_fetch_add(p, v, __ATOMIC_RELAXED, __HIP_MEMORY_SCOPE_WORKGROUP);
}
__device__ __forceinline__ int lds_add32(int* p, int v) {
    return __hip_atomic_fetch_add(p, v, __ATOMIC_RELAXED, __HIP_MEMORY_SCOPE_WORKGROUP);
}

// =============== pass 1: hist (blocks 0-255) PARALLEL misc (blocks 256-511) ===============
__global__ __launch_bounds__(256) void k_front(
    const int* __restrict__ ys, const int* __restrict__ ps,
    const float* __restrict__ params, int nP,
    const float* __restrict__ f0, const float* __restrict__ f1,
    const float* __restrict__ f2, const float* __restrict__ f3,
    int* __restrict__ histG, int* __restrict__ mmG, float* __restrict__ miscP) {
    int tid = threadIdx.x;
    int bid = blockIdx.x;
    __shared__ int hist[4][32];
    __shared__ int mm[4];
    __shared__ float red[4];

    if (bid < 256) {
        // ---- histogram + minmax for (slice, batch) ----
        int b = bid & 7;
        int sl = bid >> 3;
        int w = tid >> 6, lane = tid & 63;
        const int* yb = ys + b * NEV + sl * SLEV;
        const int* pb = ps + b * NEV + sl * SLEV;

        if (tid < 128) hist[tid >> 5][tid & 31] = 0;
        if (tid == 0) { mm[0] = INT_MAX; mm[1] = -1; mm[2] = INT_MAX; mm[3] = -1; }
        __syncthreads();

        int mnP = INT_MAX, mxP = -1, mnN = INT_MAX, mxN = -1;
        int gbase = sl * SLEV;
        for (int i = w * 64 + lane; i < SLEV; i += 256) {
            int p = pb[i];
            int y = yb[i];
            int m = (p == 1) ? 0 : 1;
            lds_add32(&hist[w][m * 16 + (y >> 4)], 1);
            int gi = gbase + i;
            if (m == 0) { mnP = min(mnP, gi); mxP = max(mxP, gi); }
            else        { mnN = min(mnN, gi); mxN = max(mxN, gi); }
        }
        for (int o = 32; o > 0; o >>= 1) {
            mnP = min(mnP, __shfl_down(mnP, o, 64));
            mxP = max(mxP, __shfl_down(mxP, o, 64));
            mnN = min(mnN, __shfl_down(mnN, o, 64));
            mxN = max(mxN, __shfl_down(mxN, o, 64));
        }
        if (lane == 0) {
            atomicMin(&mm[0], mnP); atomicMax(&mm[1], mxP);
            atomicMin(&mm[2], mnN); atomicMax(&mm[3], mxN);
        }
        __syncthreads();
        if (tid < 128) histG[(bid * 4 + (tid >> 5)) * 32 + (tid & 31)] = hist[tid >> 5][tid & 31];
        if (tid < 4)   mmG[bid * 4 + tid] = mm[tid];
        return;
    }

    // ---- misc: weight decay + smoothness -> per-block partial (no out access) ----
    float s = 0.0f;
    int gtid = (bid - 256) * 256 + tid;
    const int gstride = 256 * 256;

    int n4 = nP >> 2;
    const float4* p4 = (const float4*)params;
    float wsum = 0.0f;
    for (int i = gtid; i < n4; i += gstride) {
        float4 v = p4[i];
        wsum += v.x * v.x + v.y * v.y + v.z * v.z + v.w * v.w;
    }
    if (gtid == 0) for (int i = n4 * 4; i < nP; ++i) wsum += params[i] * params[i];
    s += wsum * 5e-5f;

    const int nTot = 1392640;
    for (int idx = gtid; idx < nTot; idx += gstride) {
        int fi, off, logW;
        if (idx < 16384)       { fi = 0; off = 0;      logW = 5; }
        else if (idx < 81920)  { fi = 1; off = 16384;  logW = 6; }
        else if (idx < 344064) { fi = 2; off = 81920;  logW = 7; }
        else                   { fi = 3; off = 344064; logW = 8; }
        const float* f = (fi == 0) ? f0 : (fi == 1) ? f1 : (fi == 2) ? f2 : f3;
        int W = 1 << logW;
        int local = idx - off;
        int x = local & (W - 1);
        int y = (local >> logW) & (W - 1);
        float c_lr = 6.25f / (float)(16 * W * (W - 1));
        float c_dd = 6.25f / (float)(16 * (W - 1) * (W - 1));
        float v = f[local];
        bool xok = x < W - 1;
        bool yok = y < W - 1;
        float vr = xok ? f[local + 1] : 0.0f;
        float vd = yok ? f[local + W] : 0.0f;
        if (xok) { float d = vr - v; s += c_lr * __powf(d * d + 1e-6f, 0.45f); }
        if (yok) { float d = vd - v; s += c_lr * __powf(d * d + 1e-6f, 0.45f); }
        if (xok && yok) {
            float d1 = f[local + W + 1] - v;
            s += c_dd * __powf(d1 * d1 + 1e-6f, 0.45f);
            float d2 = vr - vd;
            s += c_dd * __powf(d2 * d2 + 1e-6f, 0.45f);
        }
    }

    for (int o = 32; o > 0; o >>= 1) s += __shfl_down(s, o, 64);
    if ((tid & 63) == 0) red[tid >> 6] = s;
    __syncthreads();
    if (tid == 0) miscP[bid - 256] = red[0] + red[1] + red[2] + red[3];
}

// =============== pass 2: scatter (blocks 0-255) + binStart/tref/out-zero (256-263) ===============
__global__ __launch_bounds__(256) void k_scatter(
    const int* __restrict__ xs, const int* __restrict__ ys,
    const float* __restrict__ ts, const int* __restrict__ ps,
    const int* __restrict__ histG, const int* __restrict__ mmG,
    uint2* __restrict__ bins, int* __restrict__ binStart,
    float* __restrict__ tref, float* __restrict__ out) {
    int bid = blockIdx.x;
    int tid = threadIdx.x;
    __shared__ int hh[4096];        // histG for this batch: [sl][w][bin] (16 KB)
    __shared__ int curs[4][32];
    __shared__ int binTot[32];
    __shared__ int binBase[32];
    __shared__ int mm[4];

    int b = (bid < 256) ? (bid & 7) : (bid - 256);

    // stage this batch's histograms: histG idx = sl*1024 + b*128 + (w*32+bin)
    for (int i = tid; i < 4096; i += 256)
        hh[i] = histG[(i >> 7) * 1024 + b * 128 + (i & 127)];
    __syncthreads();

    if (bid >= 256) {
        // ---- per-batch binStart + tref; block 256 zeroes out ----
        if (tid < 32) {
            int tot = 0;
            for (int sl2 = 0; sl2 < 32; ++sl2) {
                #pragma unroll
                for (int w2 = 0; w2 < 4; ++w2) tot += hh[sl2 * 128 + w2 * 32 + tid];
            }
            binTot[tid] = tot;
        }
        __syncthreads();
        if (tid == 0) {
            int run = 0;
            for (int k = 0; k < 32; ++k) { binStart[b * 33 + k] = run; run += binTot[k]; }
            binStart[b * 33 + 32] = run;
            if (bid == 256) out[0] = 0.0f;
        }
        if (tid >= 64 && tid < 68) {       // minmax over 32 slice-blocks
            int c = tid - 64;
            int v = (c == 0 || c == 2) ? INT_MAX : -1;
            for (int sl2 = 0; sl2 < 32; ++sl2) {
                int x = mmG[(sl2 * 8 + b) * 4 + c];
                v = (c == 0 || c == 2) ? min(v, x) : max(v, x);
            }
            mm[c] = v;
        }
        __syncthreads();
        if (tid == 64) {
            const float* tb = ts + b * NEV;
            int mnP = mm[0], mxP = mm[1], mnN = mm[2], mxN = mm[3];
            int fP = (mnP == INT_MAX) ? 0 : mnP;
            int lP = (mxP < 0) ? (NEV - 1) : mxP;
            int fN = (mnN == INT_MAX) ? 0 : mnN;
            int lN = (mxN < 0) ? (NEV - 1) : mxN;
            tref[b * 4 + 0] = tb[lP];  // pos fwd
            tref[b * 4 + 1] = tb[fP];  // pos bwd
            tref[b * 4 + 2] = tb[lN];  // neg fwd
            tref[b * 4 + 3] = tb[fN];  // neg bwd
        }
        return;
    }

    // ---- main scatter block: recompute this (sl,b)'s cursors from hh ----
    int sl = bid >> 3;
    if (tid < 128) {
        int w = tid >> 5, bin = tid & 31;
        int pre = 0, tot = 0, wpre = 0;
        for (int sl2 = 0; sl2 < 32; ++sl2) {
            #pragma unroll
            for (int w2 = 0; w2 < 4; ++w2) {
                int v = hh[sl2 * 128 + w2 * 32 + bin];
                tot += v;
                if (sl2 < sl) pre += v;
                if (sl2 == sl && w2 < w) wpre += v;
            }
        }
        if (w == 0) binTot[bin] = tot;
        curs[w][bin] = pre + wpre;        // binBase added after prefix
    }
    __syncthreads();
    if (tid == 0) {
        int run = 0;
        for (int k = 0; k < 32; ++k) { binBase[k] = run; run += binTot[k]; }
    }
    __syncthreads();
    if (tid < 128) curs[tid >> 5][tid & 31] += binBase[tid & 31];
    __syncthreads();

    const int*   xb = xs + b * NEV + sl * SLEV;
    const int*   yb = ys + b * NEV + sl * SLEV;
    const float* tb = ts + b * NEV + sl * SLEV;
    const int*   pb = ps + b * NEV + sl * SLEV;
    uint2* ob = bins + b * NEV;
    int w = tid >> 6, lane = tid & 63;

    for (int i = w * 64 + lane; i < SLEV; i += 256) {
        int p = pb[i];
        int x = xb[i];
        int y = yb[i];
        float t = tb[i];
        int m = (p == 1) ? 0 : 1;
        int bin = m * 16 + (y >> 4);
        int pos = lds_add32(&curs[w][bin], 1);
        ob[pos] = make_uint2((unsigned)(x | (y << 8)), __float_as_uint(t));
    }
}

// =============== event splat: 512 blocks = exactly 2/CU, no tail ===============
__global__ __launch_bounds__(1024) void k_splat(
    const float* __restrict__ f0, const float* __restrict__ f1,
    const float* __restrict__ f2, const float* __restrict__ f3,
    const uint2* __restrict__ bins, const int* __restrict__ binStart,
    const float* __restrict__ tref,
    u64* __restrict__ fi0P, u64* __restrict__ fi1P,
    float* __restrict__ out) {
    __shared__ u64 acc[8192];   // 64 KB
    __shared__ float red[16];

    int tid = threadIdx.x;
    int bid = blockIdx.x;
    int b = bid & 7;
    int rm = bid >> 3;          // 0..63
    int m = rm & 1;
    int role = rm >> 1;         // 0..31
    int bm = b * 2 + m;

    int fi, row0 = 0, nrows, lo, hi, slice = 0, nslice = 1, mode;
    if (role < 4)       { fi = 0; mode = 0; slice = role;     nslice = 4; nrows = 32; lo = 0; hi = 15; }
    else if (role < 8)  { fi = 1; mode = 0; slice = role - 4; nslice = 4; nrows = 64; lo = 0; hi = 15; }
    else if (role < 16) { int c = role - 8;  fi = 2; mode = 1; row0 = 16 * c; nrows = 16;
                          lo = max(0, 2 * c - 1); hi = min(15, 2 * c + 2); }
    else                { int c = role - 16; fi = 3; mode = 1; row0 = 16 * c; nrows = 16;
                          lo = max(0, c - 1); hi = min(15, c + 1); }

    int W = 32 << fi;
    int sh = 3 - fi;
    int planeN = (fi == 0) ? 1024 : (fi == 1) ? 4096 : nrows * W;
    int used = (fi == 0) ? 8192 : 2 * planeN;
    int rowEnd = row0 + nrows;
    float Wm1 = (float)(W - 1);

    const float* flow = (fi == 0) ? f0 : (fi == 1) ? f1 : (fi == 2) ? f2 : f3;
    const float* fxp = flow + (size_t)b * 2 * W * W;
    const float* fyp = fxp + W * W;

    for (int i = tid; i < used; i += 1024) acc[i] = 0ULL;
    __syncthreads();

    float trF = tref[b * 4 + m * 2 + 0];
    float trB = tref[b * 4 + m * 2 + 1];

    int s0 = binStart[b * 33 + m * 16 + lo];
    int e0 = binStart[b * 33 + m * 16 + hi + 1];
    const uint2* eb = bins + b * NEV;

    int rep = (fi == 0) ? (((tid >> 4) & 3) * 2048) : 0;

    for (int i = s0 + slice * 1024 + tid; i < e0; i += nslice * 1024) {
        uint2 ev = eb[i];
        int x = ev.x & 255;
        int y = (ev.x >> 8) & 255;
        float t = __uint_as_float(ev.y);
        int xi = x >> sh, yi = y >> sh;
        float fx = fxp[yi * W + xi];
        float fy = fyp[yi * W + xi];
        float tF = trF - t + F32EPS;
        float tB = trB - t - F32EPS;
        #pragma unroll
        for (int dir = 0; dir < 2; ++dir) {
            float t_ = dir ? tB : tF;
            float x_ = fminf(fmaxf((float)xi + t_ * fx, 0.0f), Wm1);
            float y_ = fminf(fmaxf((float)yi + t_ * fy, 0.0f), Wm1);
            float x0f = floorf(x_), y0f = floorf(y_);
            float x0w = x_ - x0f, x1w = 1.0f - x0w;
            float y0w = y_ - y0f, y1w = 1.0f - y0w;
            int x0i = (int)x0f, y0i = (int)y0f;
            int x1i = min(x0i + 1, W - 1);
            int y1i = min(y0i + 1, W - 1);
            u64 Pa = (1ULL << 32) | (u64)(unsigned)(x0w * y0w * t * SCALE);
            u64 Pb = (1ULL << 32) | (u64)(unsigned)(x1w * y0w * t * SCALE);
            u64 Pc = (1ULL << 32) | (u64)(unsigned)(x0w * y1w * t * SCALE);
            u64 Pd = (1ULL << 32) | (u64)(unsigned)(x1w * y1w * t * SCALE);
            int base = rep + dir * planeN;
            if (mode == 0) {
                int r1 = base + y1i * W;
                int r0 = base + y0i * W;
                lds_add64(&acc[r1 + x1i], Pa);
                lds_add64(&acc[r1 + x0i], Pb);
                lds_add64(&acc[r0 + x1i], Pc);
                lds_add64(&acc[r0 + x0i], Pd);
            } else {
                if (y1i >= row0 && y1i < rowEnd) {
                    int r = base + (y1i - row0) * W;
                    lds_add64(&acc[r + x1i], Pa);
                    lds_add64(&acc[r + x0i], Pb);
                }
                if (y0i >= row0 && y0i < rowEnd) {
                    int r = base + (y0i - row0) * W;
                    lds_add64(&acc[r + x1i], Pc);
                    lds_add64(&acc[r + x0i], Pd);
                }
            }
        }
    }
    __syncthreads();

    if (mode == 0) {
        if (fi == 0) {
            for (int j = tid; j < 2048; j += 1024)
                fi0P[(bm * 4 + slice) * 2048 + j] =
                    acc[j] + acc[j + 2048] + acc[j + 4096] + acc[j + 6144];
        } else {
            for (int j = tid; j < 8192; j += 1024)
                fi1P[(bm * 4 + slice) * 8192 + j] = acc[j];
        }
        return;
    }

    float s = 0.0f;
    for (int j = tid; j < used; j += 1024) {
        u64 v = acc[j];
        float num = (float)(unsigned)(v & 0xffffffffULL) * INV_SCALE;
        float den = (float)(unsigned)(v >> 32);
        float r = num / (den + F32EPS);
        s += sqrtf(r * r + 1e-6f);
    }
    for (int o = 32; o > 0; o >>= 1) s += __shfl_down(s, o, 64);
    if ((tid & 63) == 0) red[tid >> 6] = s;
    __syncthreads();
    if (tid == 0) {
        float tot = 0.0f;
        for (int w2 = 0; w2 < 16; ++w2) tot += red[w2];
        atomicAdd(out, tot);
    }
}

// =============== merge fi0/fi1 partials + misc partials -> loss terms ===============
__global__ __launch_bounds__(256) void k_merge(const u64* __restrict__ fi0P,
                                               const u64* __restrict__ fi1P,
                                               const float* __restrict__ miscP,
                                               float* __restrict__ out) {
    int idx = blockIdx.x * 256 + threadIdx.x;   // < 163840
    u64 v = 0;
    if (idx < 32768) {
        int bm = idx >> 11, j = idx & 2047;
        const u64* p = fi0P + (bm * 4) * 2048 + j;
        #pragma unroll
        for (int s = 0; s < 4; ++s) v += p[s * 2048];
    } else {
        int r = idx - 32768;
        int bm = r >> 13, j = r & 8191;
        const u64* p = fi1P + (bm * 4) * 8192 + j;
        #pragma unroll
        for (int s = 0; s < 4; ++s) v += p[s * 8192];
    }
    float num = (float)(unsigned)(v & 0xffffffffULL) * INV_SCALE;
    float den = (float)(unsigned)(v >> 32);
    float r = num / (den + F32EPS);
    float s = sqrtf(r * r + 1e-6f);
    for (int o = 32; o > 0; o >>= 1) s += __shfl_down(s, o, 64);
    __shared__ float red[4];
    if ((threadIdx.x & 63) == 0) red[threadIdx.x >> 6] = s;
    __syncthreads();
    if (threadIdx.x == 0)
        atomicAdd(out, red[0] + red[1] + red[2] + red[3]);

    // fold in misc partials (block 0, one wave)
    if (blockIdx.x == 0 && threadIdx.x < 64) {
        float ms = 0.0f;
        for (int i = threadIdx.x; i < 256; i += 64) ms += miscP[i];
        for (int o = 32; o > 0; o >>= 1) ms += __shfl_down(ms, o, 64);
        if (threadIdx.x == 0) atomicAdd(out, ms);
    }
}

extern "C" void kernel_launch(void* const* d_in, const int* in_sizes, int n_in,
                              void* d_out, int out_size, void* d_ws, size_t ws_size,
                              hipStream_t stream) {
    const float* f0 = (const float*)d_in[0];
    const float* f1 = (const float*)d_in[1];
    const float* f2 = (const float*)d_in[2];
    const float* f3 = (const float*)d_in[3];
    const int*   xs = (const int*)d_in[4];
    const int*   ys = (const int*)d_in[5];
    const float* ts = (const float*)d_in[6];
    const int*   ps = (const int*)d_in[7];
    const float* params = (const float*)d_in[10];
    float* out = (float*)d_out;

    char* ws = (char*)d_ws;
    uint2* bins     = (uint2*)ws;
    int*   binStart = (int*)(ws + OFF_BINSTART);
    float* tref     = (float*)(ws + OFF_TREF);
    u64*   fi0P     = (u64*)(ws + OFF_FI0P);
    u64*   fi1P     = (u64*)(ws + OFF_FI1P);
    int*   histG    = (int*)(ws + OFF_HISTG);
    int*   mmG      = (int*)(ws + OFF_MMG);
    float* miscP    = (float*)(ws + OFF_MISCP);

    hipLaunchKernelGGL(k_front, dim3(512), dim3(256), 0, stream,
                       ys, ps, params, in_sizes[10], f0, f1, f2, f3, histG, mmG, miscP);
    hipLaunchKernelGGL(k_scatter, dim3(264), dim3(256), 0, stream,
                       xs, ys, ts, ps, histG, mmG, bins, binStart, tref, out);
    hipLaunchKernelGGL(k_splat, dim3(512), dim3(1024), 0, stream,
                       f0, f1, f2, f3, bins, binStart, tref, fi0P, fi1P, out);
    hipLaunchKernelGGL(k_merge, dim3(640), dim3(256), 0, stream, fi0P, fi1P, miscP, out);
}

// Round 4
// 169.201 us; speedup vs baseline: 1.7270x; 1.0870x over previous
//
#include <hip/hip_runtime.h>
#include <math.h>
#include <limits.h>

#define NEV 100000
#define NB 8
#define NSL 32                   // slices per batch
#define SLEV (NEV / NSL)         // 3125 events per slice
#define F32EPS 1.1920929e-7f
#define SCALE 524288.0f          // 2^19 fixed-point for num
#define INV_SCALE (1.0f/524288.0f)

typedef unsigned long long u64;

// ws layout (bytes):
//   0          bins: uint2[8][NEV]                 6,400,000
//   6,400,000  binStart: int[8][33]                1,056
//   6,401,056  tref: float[32]                     128
//   6,401,184  fi0P: u64[16][4][2048]              1,048,576
//   7,449,760  fi1P: u64[16][4][8192]              4,194,304
//   11,644,064 histG: int[256][4][32]              131,072
//   11,775,136 mmG:   int[256][4]                  4,096
//   11,779,232 miscP: float[1024]                  4,096
#define OFF_BINSTART 6400000
#define OFF_TREF     6401056
#define OFF_FI0P     6401184
#define OFF_FI1P     7449760
#define OFF_HISTG    11644064
#define OFF_MMG      11775136
#define OFF_MISCP    11779232

#define MISC_BLOCKS 1024

__device__ __forceinline__ void lds_add64(u64* p, u64 v) {
    __hip_atomic_fetch_add(p, v, __ATOMIC_RELAXED, __HIP_MEMORY_SCOPE_WORKGROUP);
}
__device__ __forceinline__ int lds_add32(int* p, int v) {
    return __hip_atomic_fetch_add(p, v, __ATOMIC_RELAXED, __HIP_MEMORY_SCOPE_WORKGROUP);
}

// =============== pass 1: hist (blocks 0-255) PARALLEL misc (blocks 256-1279) ===============
// misc needs ~1024 blocks of TLP to hide load latency + trans-pipe chains (R3: 12%
// occupancy at 256 blocks -> 55us; waves are cheap, 20 VGPR / 1KB LDS).
__global__ __launch_bounds__(256) void k_front(
    const int* __restrict__ ys, const int* __restrict__ ps,
    const float* __restrict__ params, int nP,
    const float* __restrict__ f0, const float* __restrict__ f1,
    const float* __restrict__ f2, const float* __restrict__ f3,
    int* __restrict__ histG, int* __restrict__ mmG, float* __restrict__ miscP) {
    int tid = threadIdx.x;
    int bid = blockIdx.x;
    __shared__ int hist[4][32];
    __shared__ int mm[4];
    __shared__ float red[4];

    if (bid < 256) {
        // ---- histogram + minmax for (slice, batch) ----
        int b = bid & 7;
        int sl = bid >> 3;
        int w = tid >> 6, lane = tid & 63;
        const int* yb = ys + b * NEV + sl * SLEV;
        const int* pb = ps + b * NEV + sl * SLEV;

        if (tid < 128) hist[tid >> 5][tid & 31] = 0;
        if (tid == 0) { mm[0] = INT_MAX; mm[1] = -1; mm[2] = INT_MAX; mm[3] = -1; }
        __syncthreads();

        int mnP = INT_MAX, mxP = -1, mnN = INT_MAX, mxN = -1;
        int gbase = sl * SLEV;
        for (int i = w * 64 + lane; i < SLEV; i += 256) {
            int p = pb[i];
            int y = yb[i];
            int m = (p == 1) ? 0 : 1;
            lds_add32(&hist[w][m * 16 + (y >> 4)], 1);
            int gi = gbase + i;
            if (m == 0) { mnP = min(mnP, gi); mxP = max(mxP, gi); }
            else        { mnN = min(mnN, gi); mxN = max(mxN, gi); }
        }
        for (int o = 32; o > 0; o >>= 1) {
            mnP = min(mnP, __shfl_down(mnP, o, 64));
            mxP = max(mxP, __shfl_down(mxP, o, 64));
            mnN = min(mnN, __shfl_down(mnN, o, 64));
            mxN = max(mxN, __shfl_down(mxN, o, 64));
        }
        if (lane == 0) {
            atomicMin(&mm[0], mnP); atomicMax(&mm[1], mxP);
            atomicMin(&mm[2], mnN); atomicMax(&mm[3], mxN);
        }
        __syncthreads();
        if (tid < 128) histG[(bid * 4 + (tid >> 5)) * 32 + (tid & 31)] = hist[tid >> 5][tid & 31];
        if (tid < 4)   mmG[bid * 4 + tid] = mm[tid];
        return;
    }

    // ---- misc: weight decay + smoothness -> per-block partial (no out access) ----
    float s = 0.0f;
    int gtid = (bid - 256) * 256 + tid;
    const int gstride = MISC_BLOCKS * 256;

    int n4 = nP >> 2;
    const float4* p4 = (const float4*)params;
    float wsum = 0.0f;
    for (int i = gtid; i < n4; i += gstride) {
        float4 v = p4[i];
        wsum += v.x * v.x + v.y * v.y + v.z * v.z + v.w * v.w;
    }
    if (gtid == 0) for (int i = n4 * 4; i < nP; ++i) wsum += params[i] * params[i];
    s += wsum * 5e-5f;

    const int nTot = 1392640;
    for (int idx = gtid; idx < nTot; idx += gstride) {
        int fi, off, logW;
        if (idx < 16384)       { fi = 0; off = 0;      logW = 5; }
        else if (idx < 81920)  { fi = 1; off = 16384;  logW = 6; }
        else if (idx < 344064) { fi = 2; off = 81920;  logW = 7; }
        else                   { fi = 3; off = 344064; logW = 8; }
        const float* f = (fi == 0) ? f0 : (fi == 1) ? f1 : (fi == 2) ? f2 : f3;
        int W = 1 << logW;
        int local = idx - off;
        int x = local & (W - 1);
        int y = (local >> logW) & (W - 1);
        float c_lr = 6.25f / (float)(16 * W * (W - 1));
        float c_dd = 6.25f / (float)(16 * (W - 1) * (W - 1));
        float v = f[local];
        bool xok = x < W - 1;
        bool yok = y < W - 1;
        float vr = xok ? f[local + 1] : 0.0f;
        float vd = yok ? f[local + W] : 0.0f;
        if (xok) { float d = vr - v; s += c_lr * __powf(d * d + 1e-6f, 0.45f); }
        if (yok) { float d = vd - v; s += c_lr * __powf(d * d + 1e-6f, 0.45f); }
        if (xok && yok) {
            float d1 = f[local + W + 1] - v;
            s += c_dd * __powf(d1 * d1 + 1e-6f, 0.45f);
            float d2 = vr - vd;
            s += c_dd * __powf(d2 * d2 + 1e-6f, 0.45f);
        }
    }

    for (int o = 32; o > 0; o >>= 1) s += __shfl_down(s, o, 64);
    if ((tid & 63) == 0) red[tid >> 6] = s;
    __syncthreads();
    if (tid == 0) miscP[bid - 256] = red[0] + red[1] + red[2] + red[3];
}

// =============== pass 2: scatter (blocks 0-255) + binStart/tref/out-zero (256-263) ===============
__global__ __launch_bounds__(256) void k_scatter(
    const int* __restrict__ xs, const int* __restrict__ ys,
    const float* __restrict__ ts, const int* __restrict__ ps,
    const int* __restrict__ histG, const int* __restrict__ mmG,
    uint2* __restrict__ bins, int* __restrict__ binStart,
    float* __restrict__ tref, float* __restrict__ out) {
    int bid = blockIdx.x;
    int tid = threadIdx.x;
    __shared__ int hh[4096];        // histG for this batch: [sl][w][bin] (16 KB)
    __shared__ int curs[4][32];
    __shared__ int binTot[32];
    __shared__ int binBase[32];
    __shared__ int mm[4];

    int b = (bid < 256) ? (bid & 7) : (bid - 256);

    // stage this batch's histograms: histG idx = sl*1024 + b*128 + (w*32+bin)
    for (int i = tid; i < 4096; i += 256)
        hh[i] = histG[(i >> 7) * 1024 + b * 128 + (i & 127)];
    __syncthreads();

    if (bid >= 256) {
        // ---- per-batch binStart + tref; block 256 zeroes out ----
        if (tid < 32) {
            int tot = 0;
            for (int sl2 = 0; sl2 < 32; ++sl2) {
                #pragma unroll
                for (int w2 = 0; w2 < 4; ++w2) tot += hh[sl2 * 128 + w2 * 32 + tid];
            }
            binTot[tid] = tot;
        }
        __syncthreads();
        if (tid == 0) {
            int run = 0;
            for (int k = 0; k < 32; ++k) { binStart[b * 33 + k] = run; run += binTot[k]; }
            binStart[b * 33 + 32] = run;
            if (bid == 256) out[0] = 0.0f;
        }
        if (tid >= 64 && tid < 68) {       // minmax over 32 slice-blocks
            int c = tid - 64;
            int v = (c == 0 || c == 2) ? INT_MAX : -1;
            for (int sl2 = 0; sl2 < 32; ++sl2) {
                int x = mmG[(sl2 * 8 + b) * 4 + c];
                v = (c == 0 || c == 2) ? min(v, x) : max(v, x);
            }
            mm[c] = v;
        }
        __syncthreads();
        if (tid == 64) {
            const float* tb = ts + b * NEV;
            int mnP = mm[0], mxP = mm[1], mnN = mm[2], mxN = mm[3];
            int fP = (mnP == INT_MAX) ? 0 : mnP;
            int lP = (mxP < 0) ? (NEV - 1) : mxP;
            int fN = (mnN == INT_MAX) ? 0 : mnN;
            int lN = (mxN < 0) ? (NEV - 1) : mxN;
            tref[b * 4 + 0] = tb[lP];  // pos fwd
            tref[b * 4 + 1] = tb[fP];  // pos bwd
            tref[b * 4 + 2] = tb[lN];  // neg fwd
            tref[b * 4 + 3] = tb[fN];  // neg bwd
        }
        return;
    }

    // ---- main scatter block: recompute this (sl,b)'s cursors from hh ----
    int sl = bid >> 3;
    if (tid < 128) {
        int w = tid >> 5, bin = tid & 31;
        int pre = 0, tot = 0, wpre = 0;
        for (int sl2 = 0; sl2 < 32; ++sl2) {
            #pragma unroll
            for (int w2 = 0; w2 < 4; ++w2) {
                int v = hh[sl2 * 128 + w2 * 32 + bin];
                tot += v;
                if (sl2 < sl) pre += v;
                if (sl2 == sl && w2 < w) wpre += v;
            }
        }
        if (w == 0) binTot[bin] = tot;
        curs[w][bin] = pre + wpre;        // binBase added after prefix
    }
    __syncthreads();
    if (tid == 0) {
        int run = 0;
        for (int k = 0; k < 32; ++k) { binBase[k] = run; run += binTot[k]; }
    }
    __syncthreads();
    if (tid < 128) curs[tid >> 5][tid & 31] += binBase[tid & 31];
    __syncthreads();

    const int*   xb = xs + b * NEV + sl * SLEV;
    const int*   yb = ys + b * NEV + sl * SLEV;
    const float* tb = ts + b * NEV + sl * SLEV;
    const int*   pb = ps + b * NEV + sl * SLEV;
    uint2* ob = bins + b * NEV;
    int w = tid >> 6, lane = tid & 63;

    for (int i = w * 64 + lane; i < SLEV; i += 256) {
        int p = pb[i];
        int x = xb[i];
        int y = yb[i];
        float t = tb[i];
        int m = (p == 1) ? 0 : 1;
        int bin = m * 16 + (y >> 4);
        int pos = lds_add32(&curs[w][bin], 1);
        ob[pos] = make_uint2((unsigned)(x | (y << 8)), __float_as_uint(t));
    }
}

// =============== event splat: 512 blocks = exactly 2/CU, no tail ===============
__global__ __launch_bounds__(1024) void k_splat(
    const float* __restrict__ f0, const float* __restrict__ f1,
    const float* __restrict__ f2, const float* __restrict__ f3,
    const uint2* __restrict__ bins, const int* __restrict__ binStart,
    const float* __restrict__ tref,
    u64* __restrict__ fi0P, u64* __restrict__ fi1P,
    float* __restrict__ out) {
    __shared__ u64 acc[8192];   // 64 KB
    __shared__ float red[16];

    int tid = threadIdx.x;
    int bid = blockIdx.x;
    int b = bid & 7;
    int rm = bid >> 3;          // 0..63
    int m = rm & 1;
    int role = rm >> 1;         // 0..31
    int bm = b * 2 + m;

    int fi, row0 = 0, nrows, lo, hi, slice = 0, nslice = 1, mode;
    if (role < 4)       { fi = 0; mode = 0; slice = role;     nslice = 4; nrows = 32; lo = 0; hi = 15; }
    else if (role < 8)  { fi = 1; mode = 0; slice = role - 4; nslice = 4; nrows = 64; lo = 0; hi = 15; }
    else if (role < 16) { int c = role - 8;  fi = 2; mode = 1; row0 = 16 * c; nrows = 16;
                          lo = max(0, 2 * c - 1); hi = min(15, 2 * c + 2); }
    else                { int c = role - 16; fi = 3; mode = 1; row0 = 16 * c; nrows = 16;
                          lo = max(0, c - 1); hi = min(15, c + 1); }

    int W = 32 << fi;
    int sh = 3 - fi;
    int planeN = (fi == 0) ? 1024 : (fi == 1) ? 4096 : nrows * W;
    int used = (fi == 0) ? 8192 : 2 * planeN;
    int rowEnd = row0 + nrows;
    float Wm1 = (float)(W - 1);

    const float* flow = (fi == 0) ? f0 : (fi == 1) ? f1 : (fi == 2) ? f2 : f3;
    const float* fxp = flow + (size_t)b * 2 * W * W;
    const float* fyp = fxp + W * W;

    for (int i = tid; i < used; i += 1024) acc[i] = 0ULL;
    __syncthreads();

    float trF = tref[b * 4 + m * 2 + 0];
    float trB = tref[b * 4 + m * 2 + 1];

    int s0 = binStart[b * 33 + m * 16 + lo];
    int e0 = binStart[b * 33 + m * 16 + hi + 1];
    const uint2* eb = bins + b * NEV;

    int rep = (fi == 0) ? (((tid >> 4) & 3) * 2048) : 0;

    for (int i = s0 + slice * 1024 + tid; i < e0; i += nslice * 1024) {
        uint2 ev = eb[i];
        int x = ev.x & 255;
        int y = (ev.x >> 8) & 255;
        float t = __uint_as_float(ev.y);
        int xi = x >> sh, yi = y >> sh;
        float fx = fxp[yi * W + xi];
        float fy = fyp[yi * W + xi];
        float tF = trF - t + F32EPS;
        float tB = trB - t - F32EPS;
        #pragma unroll
        for (int dir = 0; dir < 2; ++dir) {
            float t_ = dir ? tB : tF;
            float x_ = fminf(fmaxf((float)xi + t_ * fx, 0.0f), Wm1);
            float y_ = fminf(fmaxf((float)yi + t_ * fy, 0.0f), Wm1);
            float x0f = floorf(x_), y0f = floorf(y_);
            float x0w = x_ - x0f, x1w = 1.0f - x0w;
            float y0w = y_ - y0f, y1w = 1.0f - y0w;
            int x0i = (int)x0f, y0i = (int)y0f;
            int x1i = min(x0i + 1, W - 1);
            int y1i = min(y0i + 1, W - 1);
            u64 Pa = (1ULL << 32) | (u64)(unsigned)(x0w * y0w * t * SCALE);
            u64 Pb = (1ULL << 32) | (u64)(unsigned)(x1w * y0w * t * SCALE);
            u64 Pc = (1ULL << 32) | (u64)(unsigned)(x0w * y1w * t * SCALE);
            u64 Pd = (1ULL << 32) | (u64)(unsigned)(x1w * y1w * t * SCALE);
            int base = rep + dir * planeN;
            if (mode == 0) {
                int r1 = base + y1i * W;
                int r0 = base + y0i * W;
                lds_add64(&acc[r1 + x1i], Pa);
                lds_add64(&acc[r1 + x0i], Pb);
                lds_add64(&acc[r0 + x1i], Pc);
                lds_add64(&acc[r0 + x0i], Pd);
            } else {
                if (y1i >= row0 && y1i < rowEnd) {
                    int r = base + (y1i - row0) * W;
                    lds_add64(&acc[r + x1i], Pa);
                    lds_add64(&acc[r + x0i], Pb);
                }
                if (y0i >= row0 && y0i < rowEnd) {
                    int r = base + (y0i - row0) * W;
                    lds_add64(&acc[r + x1i], Pc);
                    lds_add64(&acc[r + x0i], Pd);
                }
            }
        }
    }
    __syncthreads();

    if (mode == 0) {
        if (fi == 0) {
            for (int j = tid; j < 2048; j += 1024)
                fi0P[(bm * 4 + slice) * 2048 + j] =
                    acc[j] + acc[j + 2048] + acc[j + 4096] + acc[j + 6144];
        } else {
            for (int j = tid; j < 8192; j += 1024)
                fi1P[(bm * 4 + slice) * 8192 + j] = acc[j];
        }
        return;
    }

    float s = 0.0f;
    for (int j = tid; j < used; j += 1024) {
        u64 v = acc[j];
        float num = (float)(unsigned)(v & 0xffffffffULL) * INV_SCALE;
        float den = (float)(unsigned)(v >> 32);
        float r = num / (den + F32EPS);
        s += sqrtf(r * r + 1e-6f);
    }
    for (int o = 32; o > 0; o >>= 1) s += __shfl_down(s, o, 64);
    if ((tid & 63) == 0) red[tid >> 6] = s;
    __syncthreads();
    if (tid == 0) {
        float tot = 0.0f;
        for (int w2 = 0; w2 < 16; ++w2) tot += red[w2];
        atomicAdd(out, tot);
    }
}

// =============== merge fi0/fi1 partials + misc partials -> loss terms ===============
__global__ __launch_bounds__(256) void k_merge(const u64* __restrict__ fi0P,
                                               const u64* __restrict__ fi1P,
                                               const float* __restrict__ miscP,
                                               float* __restrict__ out) {
    int idx = blockIdx.x * 256 + threadIdx.x;   // < 163840
    u64 v = 0;
    if (idx < 32768) {
        int bm = idx >> 11, j = idx & 2047;
        const u64* p = fi0P + (bm * 4) * 2048 + j;
        #pragma unroll
        for (int s = 0; s < 4; ++s) v += p[s * 2048];
    } else {
        int r = idx - 32768;
        int bm = r >> 13, j = r & 8191;
        const u64* p = fi1P + (bm * 4) * 8192 + j;
        #pragma unroll
        for (int s = 0; s < 4; ++s) v += p[s * 8192];
    }
    float num = (float)(unsigned)(v & 0xffffffffULL) * INV_SCALE;
    float den = (float)(unsigned)(v >> 32);
    float r = num / (den + F32EPS);
    float s = sqrtf(r * r + 1e-6f);

    // fold in misc partials (block 0 only): add per-thread before reduction
    if (blockIdx.x == 0) {
        float ms = miscP[threadIdx.x] + miscP[threadIdx.x + 256]
                 + miscP[threadIdx.x + 512] + miscP[threadIdx.x + 768];
        s += ms;
    }

    for (int o = 32; o > 0; o >>= 1) s += __shfl_down(s, o, 64);
    __shared__ float red[4];
    if ((threadIdx.x & 63) == 0) red[threadIdx.x >> 6] = s;
    __syncthreads();
    if (threadIdx.x == 0)
        atomicAdd(out, red[0] + red[1] + red[2] + red[3]);
}

extern "C" void kernel_launch(void* const* d_in, const int* in_sizes, int n_in,
                              void* d_out, int out_size, void* d_ws, size_t ws_size,
                              hipStream_t stream) {
    const float* f0 = (const float*)d_in[0];
    const float* f1 = (const float*)d_in[1];
    const float* f2 = (const float*)d_in[2];
    const float* f3 = (const float*)d_in[3];
    const int*   xs = (const int*)d_in[4];
    const int*   ys = (const int*)d_in[5];
    const float* ts = (const float*)d_in[6];
    const int*   ps = (const int*)d_in[7];
    const float* params = (const float*)d_in[10];
    float* out = (float*)d_out;

    char* ws = (char*)d_ws;
    uint2* bins     = (uint2*)ws;
    int*   binStart = (int*)(ws + OFF_BINSTART);
    float* tref     = (float*)(ws + OFF_TREF);
    u64*   fi0P     = (u64*)(ws + OFF_FI0P);
    u64*   fi1P     = (u64*)(ws + OFF_FI1P);
    int*   histG    = (int*)(ws + OFF_HISTG);
    int*   mmG      = (int*)(ws + OFF_MMG);
    float* miscP    = (float*)(ws + OFF_MISCP);

    hipLaunchKernelGGL(k_front, dim3(256 + MISC_BLOCKS), dim3(256), 0, stream,
                       ys, ps, params, in_sizes[10], f0, f1, f2, f3, histG, mmG, miscP);
    hipLaunchKernelGGL(k_scatter, dim3(264), dim3(256), 0, stream,
                       xs, ys, ts, ps, histG, mmG, bins, binStart, tref, out);
    hipLaunchKernelGGL(k_splat, dim3(512), dim3(1024), 0, stream,
                       f0, f1, f2, f3, bins, binStart, tref, fi0P, fi1P, out);
    hipLaunchKernelGGL(k_merge, dim3(640), dim3(256), 0, stream, fi0P, fi1P, miscP, out);
}

// Round 6
// 154.787 us; speedup vs baseline: 1.8878x; 1.0931x over previous
//
#include <hip/hip_runtime.h>
#include <math.h>
#include <limits.h>

#define NEV 100000
#define NB 8
#define NSL 32                   // slices per batch
#define SLEV (NEV / NSL)         // 3125 events per slice
#define F32EPS 1.1920929e-7f
#define SCALE 524288.0f          // 2^19 fixed-point for num
#define INV_SCALE (1.0f/524288.0f)

typedef unsigned long long u64;

// ws layout (bytes):
//   0          bins: uint2[8][NEV]                 6,400,000
//   6,400,000  binStart: int[8][33]                1,056
//   6,401,056  tref: float[32]                     128
//   6,401,184  fi0P: u64[16][4][2048]              1,048,576
//   7,449,760  fi1P: u64[16][4][8192]              4,194,304
//   11,644,064 histG: int[256][4][32]              131,072
//   11,775,136 mmG:   int[256][4]                  4,096
//   11,779,232 miscP: float[1024]                  4,096
#define OFF_BINSTART 6400000
#define OFF_TREF     6401056
#define OFF_FI0P     6401184
#define OFF_FI1P     7449760
#define OFF_HISTG    11644064
#define OFF_MMG      11775136
#define OFF_MISCP    11779232

#define MISC_BLOCKS 1024

__device__ __forceinline__ void lds_add64(u64* p, u64 v) {
    __hip_atomic_fetch_add(p, v, __ATOMIC_RELAXED, __HIP_MEMORY_SCOPE_WORKGROUP);
}
__device__ __forceinline__ int lds_add32(int* p, int v) {
    return __hip_atomic_fetch_add(p, v, __ATOMIC_RELAXED, __HIP_MEMORY_SCOPE_WORKGROUP);
}

// fast z^0.45 for z > 0: v_log_f32 (log2) + v_mul + v_exp_f32 (2^x) — 3 ops.
// __powf lowers to the full OCML pow path (~150 ops); at 5.57M calls that was
// ~40-50 us of the smoothness pass (R2-R4 forensics). amdgcn builtins lower
// 1:1 to the trans-pipe instructions — no libcall, device-safe on gfx950.
__device__ __forceinline__ float pow045(float z) {
    return __builtin_amdgcn_exp2f(0.45f * __builtin_amdgcn_logf(z));
}

// =============== pass 1: hist (blocks 0-255) PARALLEL misc (blocks 256-1279) ===============
__global__ __launch_bounds__(256) void k_front(
    const int* __restrict__ ys, const int* __restrict__ ps,
    const float* __restrict__ params, int nP,
    const float* __restrict__ f0, const float* __restrict__ f1,
    const float* __restrict__ f2, const float* __restrict__ f3,
    int* __restrict__ histG, int* __restrict__ mmG, float* __restrict__ miscP) {
    int tid = threadIdx.x;
    int bid = blockIdx.x;
    __shared__ int hist[4][32];
    __shared__ int mm[4];
    __shared__ float red[4];

    if (bid < 256) {
        // ---- histogram + minmax for (slice, batch) ----
        int b = bid & 7;
        int sl = bid >> 3;
        int w = tid >> 6, lane = tid & 63;
        const int* yb = ys + b * NEV + sl * SLEV;
        const int* pb = ps + b * NEV + sl * SLEV;

        if (tid < 128) hist[tid >> 5][tid & 31] = 0;
        if (tid == 0) { mm[0] = INT_MAX; mm[1] = -1; mm[2] = INT_MAX; mm[3] = -1; }
        __syncthreads();

        int mnP = INT_MAX, mxP = -1, mnN = INT_MAX, mxN = -1;
        int gbase = sl * SLEV;
        for (int i = w * 64 + lane; i < SLEV; i += 256) {
            int p = pb[i];
            int y = yb[i];
            int m = (p == 1) ? 0 : 1;
            lds_add32(&hist[w][m * 16 + (y >> 4)], 1);
            int gi = gbase + i;
            if (m == 0) { mnP = min(mnP, gi); mxP = max(mxP, gi); }
            else        { mnN = min(mnN, gi); mxN = max(mxN, gi); }
        }
        for (int o = 32; o > 0; o >>= 1) {
            mnP = min(mnP, __shfl_down(mnP, o, 64));
            mxP = max(mxP, __shfl_down(mxP, o, 64));
            mnN = min(mnN, __shfl_down(mnN, o, 64));
            mxN = max(mxN, __shfl_down(mxN, o, 64));
        }
        if (lane == 0) {
            atomicMin(&mm[0], mnP); atomicMax(&mm[1], mxP);
            atomicMin(&mm[2], mnN); atomicMax(&mm[3], mxN);
        }
        __syncthreads();
        if (tid < 128) histG[(bid * 4 + (tid >> 5)) * 32 + (tid & 31)] = hist[tid >> 5][tid & 31];
        if (tid < 4)   mmG[bid * 4 + tid] = mm[tid];
        return;
    }

    // ---- misc: weight decay + smoothness -> per-block partial (no out access) ----
    float s = 0.0f;
    int gtid = (bid - 256) * 256 + tid;
    const int gstride = MISC_BLOCKS * 256;

    int n4 = nP >> 2;
    const float4* p4 = (const float4*)params;
    float wsum = 0.0f;
    for (int i = gtid; i < n4; i += gstride) {
        float4 v = p4[i];
        wsum += v.x * v.x + v.y * v.y + v.z * v.z + v.w * v.w;
    }
    if (gtid == 0) for (int i = n4 * 4; i < nP; ++i) wsum += params[i] * params[i];
    s += wsum * 5e-5f;

    const int nTot = 1392640;
    for (int idx = gtid; idx < nTot; idx += gstride) {
        int fi, off, logW;
        if (idx < 16384)       { fi = 0; off = 0;      logW = 5; }
        else if (idx < 81920)  { fi = 1; off = 16384;  logW = 6; }
        else if (idx < 344064) { fi = 2; off = 81920;  logW = 7; }
        else                   { fi = 3; off = 344064; logW = 8; }
        const float* f = (fi == 0) ? f0 : (fi == 1) ? f1 : (fi == 2) ? f2 : f3;
        int W = 1 << logW;
        int local = idx - off;
        int x = local & (W - 1);
        int y = (local >> logW) & (W - 1);
        float c_lr = 6.25f / (float)(16 * W * (W - 1));
        float c_dd = 6.25f / (float)(16 * (W - 1) * (W - 1));
        float v = f[local];
        bool xok = x < W - 1;
        bool yok = y < W - 1;
        float vr = xok ? f[local + 1] : 0.0f;
        float vd = yok ? f[local + W] : 0.0f;
        if (xok) { float d = vr - v; s += c_lr * pow045(d * d + 1e-6f); }
        if (yok) { float d = vd - v; s += c_lr * pow045(d * d + 1e-6f); }
        if (xok && yok) {
            float d1 = f[local + W + 1] - v;
            s += c_dd * pow045(d1 * d1 + 1e-6f);
            float d2 = vr - vd;
            s += c_dd * pow045(d2 * d2 + 1e-6f);
        }
    }

    for (int o = 32; o > 0; o >>= 1) s += __shfl_down(s, o, 64);
    if ((tid & 63) == 0) red[tid >> 6] = s;
    __syncthreads();
    if (tid == 0) miscP[bid - 256] = red[0] + red[1] + red[2] + red[3];
}

// =============== pass 2: scatter (blocks 0-255) + binStart/tref/out-zero (256-263) ===============
__global__ __launch_bounds__(256) void k_scatter(
    const int* __restrict__ xs, const int* __restrict__ ys,
    const float* __restrict__ ts, const int* __restrict__ ps,
    const int* __restrict__ histG, const int* __restrict__ mmG,
    uint2* __restrict__ bins, int* __restrict__ binStart,
    float* __restrict__ tref, float* __restrict__ out) {
    int bid = blockIdx.x;
    int tid = threadIdx.x;
    __shared__ int hh[4096];        // histG for this batch: [sl][w][bin] (16 KB)
    __shared__ int curs[4][32];
    __shared__ int binTot[32];
    __shared__ int binBase[32];
    __shared__ int mm[4];

    int b = (bid < 256) ? (bid & 7) : (bid - 256);

    // stage this batch's histograms: histG idx = sl*1024 + b*128 + (w*32+bin)
    for (int i = tid; i < 4096; i += 256)
        hh[i] = histG[(i >> 7) * 1024 + b * 128 + (i & 127)];
    __syncthreads();

    if (bid >= 256) {
        // ---- per-batch binStart + tref; block 256 zeroes out ----
        if (tid < 32) {
            int tot = 0;
            for (int sl2 = 0; sl2 < 32; ++sl2) {
                #pragma unroll
                for (int w2 = 0; w2 < 4; ++w2) tot += hh[sl2 * 128 + w2 * 32 + tid];
            }
            binTot[tid] = tot;
        }
        __syncthreads();
        if (tid == 0) {
            int run = 0;
            for (int k = 0; k < 32; ++k) { binStart[b * 33 + k] = run; run += binTot[k]; }
            binStart[b * 33 + 32] = run;
            if (bid == 256) out[0] = 0.0f;
        }
        if (tid >= 64 && tid < 68) {       // minmax over 32 slice-blocks
            int c = tid - 64;
            int v = (c == 0 || c == 2) ? INT_MAX : -1;
            for (int sl2 = 0; sl2 < 32; ++sl2) {
                int x = mmG[(sl2 * 8 + b) * 4 + c];
                v = (c == 0 || c == 2) ? min(v, x) : max(v, x);
            }
            mm[c] = v;
        }
        __syncthreads();
        if (tid == 64) {
            const float* tb = ts + b * NEV;
            int mnP = mm[0], mxP = mm[1], mnN = mm[2], mxN = mm[3];
            int fP = (mnP == INT_MAX) ? 0 : mnP;
            int lP = (mxP < 0) ? (NEV - 1) : mxP;
            int fN = (mnN == INT_MAX) ? 0 : mnN;
            int lN = (mxN < 0) ? (NEV - 1) : mxN;
            tref[b * 4 + 0] = tb[lP];  // pos fwd
            tref[b * 4 + 1] = tb[fP];  // pos bwd
            tref[b * 4 + 2] = tb[lN];  // neg fwd
            tref[b * 4 + 3] = tb[fN];  // neg bwd
        }
        return;
    }

    // ---- main scatter block: recompute this (sl,b)'s cursors from hh ----
    int sl = bid >> 3;
    if (tid < 128) {
        int w = tid >> 5, bin = tid & 31;
        int pre = 0, tot = 0, wpre = 0;
        for (int sl2 = 0; sl2 < 32; ++sl2) {
            #pragma unroll
            for (int w2 = 0; w2 < 4; ++w2) {
                int v = hh[sl2 * 128 + w2 * 32 + bin];
                tot += v;
                if (sl2 < sl) pre += v;
                if (sl2 == sl && w2 < w) wpre += v;
            }
        }
        if (w == 0) binTot[bin] = tot;
        curs[w][bin] = pre + wpre;        // binBase added after prefix
    }
    __syncthreads();
    if (tid == 0) {
        int run = 0;
        for (int k = 0; k < 32; ++k) { binBase[k] = run; run += binTot[k]; }
    }
    __syncthreads();
    if (tid < 128) curs[tid >> 5][tid & 31] += binBase[tid & 31];
    __syncthreads();

    const int*   xb = xs + b * NEV + sl * SLEV;
    const int*   yb = ys + b * NEV + sl * SLEV;
    const float* tb = ts + b * NEV + sl * SLEV;
    const int*   pb = ps + b * NEV + sl * SLEV;
    uint2* ob = bins + b * NEV;
    int w = tid >> 6, lane = tid & 63;

    for (int i = w * 64 + lane; i < SLEV; i += 256) {
        int p = pb[i];
        int x = xb[i];
        int y = yb[i];
        float t = tb[i];
        int m = (p == 1) ? 0 : 1;
        int bin = m * 16 + (y >> 4);
        int pos = lds_add32(&curs[w][bin], 1);
        ob[pos] = make_uint2((unsigned)(x | (y << 8)), __float_as_uint(t));
    }
}

// =============== event splat: 512 blocks = exactly 2/CU, no tail ===============
__global__ __launch_bounds__(1024) void k_splat(
    const float* __restrict__ f0, const float* __restrict__ f1,
    const float* __restrict__ f2, const float* __restrict__ f3,
    const uint2* __restrict__ bins, const int* __restrict__ binStart,
    const float* __restrict__ tref,
    u64* __restrict__ fi0P, u64* __restrict__ fi1P,
    float* __restrict__ out) {
    __shared__ u64 acc[8192];   // 64 KB
    __shared__ float red[16];

    int tid = threadIdx.x;
    int bid = blockIdx.x;
    int b = bid & 7;
    int rm = bid >> 3;          // 0..63
    int m = rm & 1;
    int role = rm >> 1;         // 0..31
    int bm = b * 2 + m;

    int fi, row0 = 0, nrows, lo, hi, slice = 0, nslice = 1, mode;
    if (role < 4)       { fi = 0; mode = 0; slice = role;     nslice = 4; nrows = 32; lo = 0; hi = 15; }
    else if (role < 8)  { fi = 1; mode = 0; slice = role - 4; nslice = 4; nrows = 64; lo = 0; hi = 15; }
    else if (role < 16) { int c = role - 8;  fi = 2; mode = 1; row0 = 16 * c; nrows = 16;
                          lo = max(0, 2 * c - 1); hi = min(15, 2 * c + 2); }
    else                { int c = role - 16; fi = 3; mode = 1; row0 = 16 * c; nrows = 16;
                          lo = max(0, c - 1); hi = min(15, c + 1); }

    int W = 32 << fi;
    int sh = 3 - fi;
    int planeN = (fi == 0) ? 1024 : (fi == 1) ? 4096 : nrows * W;
    int used = (fi == 0) ? 8192 : 2 * planeN;
    int rowEnd = row0 + nrows;
    float Wm1 = (float)(W - 1);

    const float* flow = (fi == 0) ? f0 : (fi == 1) ? f1 : (fi == 2) ? f2 : f3;
    const float* fxp = flow + (size_t)b * 2 * W * W;
    const float* fyp = fxp + W * W;

    for (int i = tid; i < used; i += 1024) acc[i] = 0ULL;
    __syncthreads();

    float trF = tref[b * 4 + m * 2 + 0];
    float trB = tref[b * 4 + m * 2 + 1];

    int s0 = binStart[b * 33 + m * 16 + lo];
    int e0 = binStart[b * 33 + m * 16 + hi + 1];
    const uint2* eb = bins + b * NEV;

    int rep = (fi == 0) ? (((tid >> 4) & 3) * 2048) : 0;

    for (int i = s0 + slice * 1024 + tid; i < e0; i += nslice * 1024) {
        uint2 ev = eb[i];
        int x = ev.x & 255;
        int y = (ev.x >> 8) & 255;
        float t = __uint_as_float(ev.y);
        int xi = x >> sh, yi = y >> sh;
        float fx = fxp[yi * W + xi];
        float fy = fyp[yi * W + xi];
        float tF = trF - t + F32EPS;
        float tB = trB - t - F32EPS;
        #pragma unroll
        for (int dir = 0; dir < 2; ++dir) {
            float t_ = dir ? tB : tF;
            float x_ = fminf(fmaxf((float)xi + t_ * fx, 0.0f), Wm1);
            float y_ = fminf(fmaxf((float)yi + t_ * fy, 0.0f), Wm1);
            float x0f = floorf(x_), y0f = floorf(y_);
            float x0w = x_ - x0f, x1w = 1.0f - x0w;
            float y0w = y_ - y0f, y1w = 1.0f - y0w;
            int x0i = (int)x0f, y0i = (int)y0f;
            int x1i = min(x0i + 1, W - 1);
            int y1i = min(y0i + 1, W - 1);
            u64 Pa = (1ULL << 32) | (u64)(unsigned)(x0w * y0w * t * SCALE);
            u64 Pb = (1ULL << 32) | (u64)(unsigned)(x1w * y0w * t * SCALE);
            u64 Pc = (1ULL << 32) | (u64)(unsigned)(x0w * y1w * t * SCALE);
            u64 Pd = (1ULL << 32) | (u64)(unsigned)(x1w * y1w * t * SCALE);
            int base = rep + dir * planeN;
            if (mode == 0) {
                int r1 = base + y1i * W;
                int r0 = base + y0i * W;
                lds_add64(&acc[r1 + x1i], Pa);
                lds_add64(&acc[r1 + x0i], Pb);
                lds_add64(&acc[r0 + x1i], Pc);
                lds_add64(&acc[r0 + x0i], Pd);
            } else {
                if (y1i >= row0 && y1i < rowEnd) {
                    int r = base + (y1i - row0) * W;
                    lds_add64(&acc[r + x1i], Pa);
                    lds_add64(&acc[r + x0i], Pb);
                }
                if (y0i >= row0 && y0i < rowEnd) {
                    int r = base + (y0i - row0) * W;
                    lds_add64(&acc[r + x1i], Pc);
                    lds_add64(&acc[r + x0i], Pd);
                }
            }
        }
    }
    __syncthreads();

    if (mode == 0) {
        if (fi == 0) {
            for (int j = tid; j < 2048; j += 1024)
                fi0P[(bm * 4 + slice) * 2048 + j] =
                    acc[j] + acc[j + 2048] + acc[j + 4096] + acc[j + 6144];
        } else {
            for (int j = tid; j < 8192; j += 1024)
                fi1P[(bm * 4 + slice) * 8192 + j] = acc[j];
        }
        return;
    }

    float s = 0.0f;
    for (int j = tid; j < used; j += 1024) {
        u64 v = acc[j];
        float num = (float)(unsigned)(v & 0xffffffffULL) * INV_SCALE;
        float den = (float)(unsigned)(v >> 32);
        float r = num / (den + F32EPS);
        s += sqrtf(r * r + 1e-6f);
    }
    for (int o = 32; o > 0; o >>= 1) s += __shfl_down(s, o, 64);
    if ((tid & 63) == 0) red[tid >> 6] = s;
    __syncthreads();
    if (tid == 0) {
        float tot = 0.0f;
        for (int w2 = 0; w2 < 16; ++w2) tot += red[w2];
        atomicAdd(out, tot);
    }
}

// =============== merge fi0/fi1 partials + misc partials -> loss terms ===============
__global__ __launch_bounds__(256) void k_merge(const u64* __restrict__ fi0P,
                                               const u64* __restrict__ fi1P,
                                               const float* __restrict__ miscP,
                                               float* __restrict__ out) {
    int idx = blockIdx.x * 256 + threadIdx.x;   // < 163840
    u64 v = 0;
    if (idx < 32768) {
        int bm = idx >> 11, j = idx & 2047;
        const u64* p = fi0P + (bm * 4) * 2048 + j;
        #pragma unroll
        for (int s = 0; s < 4; ++s) v += p[s * 2048];
    } else {
        int r = idx - 32768;
        int bm = r >> 13, j = r & 8191;
        const u64* p = fi1P + (bm * 4) * 8192 + j;
        #pragma unroll
        for (int s = 0; s < 4; ++s) v += p[s * 8192];
    }
    float num = (float)(unsigned)(v & 0xffffffffULL) * INV_SCALE;
    float den = (float)(unsigned)(v >> 32);
    float r = num / (den + F32EPS);
    float s = sqrtf(r * r + 1e-6f);

    // fold in misc partials (block 0 only): add per-thread before reduction
    if (blockIdx.x == 0) {
        float ms = miscP[threadIdx.x] + miscP[threadIdx.x + 256]
                 + miscP[threadIdx.x + 512] + miscP[threadIdx.x + 768];
        s += ms;
    }

    for (int o = 32; o > 0; o >>= 1) s += __shfl_down(s, o, 64);
    __shared__ float red[4];
    if ((threadIdx.x & 63) == 0) red[threadIdx.x >> 6] = s;
    __syncthreads();
    if (threadIdx.x == 0)
        atomicAdd(out, red[0] + red[1] + red[2] + red[3]);
}

extern "C" void kernel_launch(void* const* d_in, const int* in_sizes, int n_in,
                              void* d_out, int out_size, void* d_ws, size_t ws_size,
                              hipStream_t stream) {
    const float* f0 = (const float*)d_in[0];
    const float* f1 = (const float*)d_in[1];
    const float* f2 = (const float*)d_in[2];
    const float* f3 = (const float*)d_in[3];
    const int*   xs = (const int*)d_in[4];
    const int*   ys = (const int*)d_in[5];
    const float* ts = (const float*)d_in[6];
    const int*   ps = (const int*)d_in[7];
    const float* params = (const float*)d_in[10];
    float* out = (float*)d_out;

    char* ws = (char*)d_ws;
    uint2* bins     = (uint2*)ws;
    int*   binStart = (int*)(ws + OFF_BINSTART);
    float* tref     = (float*)(ws + OFF_TREF);
    u64*   fi0P     = (u64*)(ws + OFF_FI0P);
    u64*   fi1P     = (u64*)(ws + OFF_FI1P);
    int*   histG    = (int*)(ws + OFF_HISTG);
    int*   mmG      = (int*)(ws + OFF_MMG);
    float* miscP    = (float*)(ws + OFF_MISCP);

    hipLaunchKernelGGL(k_front, dim3(256 + MISC_BLOCKS), dim3(256), 0, stream,
                       ys, ps, params, in_sizes[10], f0, f1, f2, f3, histG, mmG, miscP);
    hipLaunchKernelGGL(k_scatter, dim3(264), dim3(256), 0, stream,
                       xs, ys, ts, ps, histG, mmG, bins, binStart, tref, out);
    hipLaunchKernelGGL(k_splat, dim3(512), dim3(1024), 0, stream,
                       f0, f1, f2, f3, bins, binStart, tref, fi0P, fi1P, out);
    hipLaunchKernelGGL(k_merge, dim3(640), dim3(256), 0, stream, fi0P, fi1P, miscP, out);
}